// Round 2
// baseline (427.952 us; speedup 1.0000x reference)
//
#include <hip/hip_runtime.h>
#include <hip/hip_bf16.h>

// ReadInAttention restructured (all f32 I/O per reference dtypes):
//  r = LN(receiver_states); s = LN(sender_states)
//  mq,mk,mv,me = 1 + codes @ Wm*
//  q = (r∘mq) @ Wq + bq
//  qm[m,h,d]  = mk[m,d] * Σ_c q[m,hc]·Wk[d,hc];  qbk[m,h] = Σ_c q[m,hc]·bk[hc]
//  scores[m,h,v] = (Σ_d qm[m,h,d]·s[b,v,d] + qbk[m,h]) / 8 ; w = softmax_v
//  wsm[m,h,d] = mv[m,d] * Σ_v w[m,h,v]·s[b,v,d]
//  mm[m,i]    = me[m,i] * (Σ_d wsm[m,h(i),d]·Wv[d,i] + bv[i])
//  out[m,d]   = rs[m,d] + (Σ_i mm[m,i]·We[i,d] + be[d]) * gamma[d]

#define BB 4
#define UU 64
#define VV 256
#define DD 768
#define CDIM 384
#define NH 8
#define HD 64
#define INNER 512
#define MM_ROWS (BB*UU)   // 256

// ---------------- LayerNorm (rows x 768), f32 in, f32 out ----------------
__global__ __launch_bounds__(256) void ln_kernel(
    const float* __restrict__ x, const float* __restrict__ g,
    const float* __restrict__ bta, float* __restrict__ y) {
  int row = blockIdx.x;
  int t = threadIdx.x;
  const float* xr = x + (size_t)row * DD;
  float v0 = xr[t];
  float v1 = xr[t + 256];
  float v2 = xr[t + 512];
  float s = v0 + v1 + v2;
  float ss = v0 * v0 + v1 * v1 + v2 * v2;
  for (int o = 32; o > 0; o >>= 1) {
    s  += __shfl_down(s, o, 64);
    ss += __shfl_down(ss, o, 64);
  }
  __shared__ float red[8];
  int wid = t >> 6, lane = t & 63;
  if (lane == 0) { red[wid] = s; red[wid + 4] = ss; }
  __syncthreads();
  float sum = red[0] + red[1] + red[2] + red[3];
  float sq  = red[4] + red[5] + red[6] + red[7];
  float mu = sum * (1.0f / 768.0f);
  float var = sq * (1.0f / 768.0f) - mu * mu;
  float rstd = rsqrtf(var + 1e-5f);
  float* yr = y + (size_t)row * DD;
  yr[t]       = (v0 - mu) * rstd * g[t]       + bta[t];
  yr[t + 256] = (v1 - mu) * rstd * g[t + 256] + bta[t + 256];
  yr[t + 512] = (v2 - mu) * rstd * g[t + 512] + bta[t + 512];
}

// ------- mq/mk/mv/me = 1 + codes @ Wm*  (4 rows per block, 256 cols) -------
__global__ __launch_bounds__(256) void code_gemm(
    const float* __restrict__ codes, const float* __restrict__ Wmq,
    const float* __restrict__ Wmk, const float* __restrict__ Wmv,
    const float* __restrict__ Wme, float* __restrict__ mq, float* __restrict__ mk,
    float* __restrict__ mv, float* __restrict__ me) {
  int mg = blockIdx.x;  // 64 groups of 4 rows
  int cc = blockIdx.y;  // 11 chunks: 0-2 mq, 3-5 mk, 6-8 mv, 9-10 me
  int t = threadIdx.x;
  const float* W; float* out; int N, col0;
  if (cc < 3)      { W = Wmq; out = mq; N = DD;    col0 = cc * 256; }
  else if (cc < 6) { W = Wmk; out = mk; N = DD;    col0 = (cc - 3) * 256; }
  else if (cc < 9) { W = Wmv; out = mv; N = DD;    col0 = (cc - 6) * 256; }
  else             { W = Wme; out = me; N = INNER; col0 = (cc - 9) * 256; }
  __shared__ float cl[4][CDIM];
  int m0 = mg * 4;
  for (int i = t; i < 4 * CDIM; i += 256) {
    int r = i / CDIM, c = i % CDIM;
    cl[r][c] = codes[(size_t)(m0 + r) * CDIM + c];
  }
  __syncthreads();
  int col = col0 + t;
  const float* Wc = W + col;
  float a0 = 0.f, a1 = 0.f, a2 = 0.f, a3 = 0.f;
#pragma unroll 8
  for (int c = 0; c < CDIM; c++) {
    float wv = Wc[(size_t)c * N];
    a0 += cl[0][c] * wv; a1 += cl[1][c] * wv;
    a2 += cl[2][c] * wv; a3 += cl[3][c] * wv;
  }
  out[(size_t)(m0 + 0) * N + col] = 1.0f + a0;
  out[(size_t)(m0 + 1) * N + col] = 1.0f + a1;
  out[(size_t)(m0 + 2) * N + col] = 1.0f + a2;
  out[(size_t)(m0 + 3) * N + col] = 1.0f + a3;
}

// ---------------- q = (r∘mq) @ Wq + bq  (2 rows, 256 cols / block) ---------
__global__ __launch_bounds__(256) void q_gemm(
    const float* __restrict__ r_ln, const float* __restrict__ mq,
    const float* __restrict__ Wq, const float* __restrict__ bq,
    float* __restrict__ q) {
  int mg = blockIdx.x, cc = blockIdx.y, t = threadIdx.x;
  int m0 = mg * 2;
  __shared__ float a[2][DD];
  for (int i = t; i < 2 * DD; i += 256) {
    int r = i / DD, d = i % DD;
    a[r][d] = r_ln[(size_t)(m0 + r) * DD + d] * mq[(size_t)(m0 + r) * DD + d];
  }
  __syncthreads();
  int col = cc * 256 + t;
  const float* Wc = Wq + col;
  float a0 = 0.f, a1 = 0.f;
#pragma unroll 8
  for (int d = 0; d < DD; d++) {
    float wv = Wc[(size_t)d * INNER];
    a0 += a[0][d] * wv; a1 += a[1][d] * wv;
  }
  float bb = bq[col];
  q[(size_t)m0 * INNER + col] = a0 + bb;
  q[(size_t)(m0 + 1) * INNER + col] = a1 + bb;
}

// ------- qm[m,h,d] = mk[m,d]*Σ_c q[m,hc]Wk[d,hc];  qbk[m,h] ---------------
__global__ __launch_bounds__(256) void qmk_kernel(
    const float* __restrict__ q, const float* __restrict__ mkp,
    const float* __restrict__ Wk, const float* __restrict__ bkp,
    float* __restrict__ qm, float* __restrict__ qbk) {
  int m = blockIdx.x;
  int h0 = blockIdx.y * 4;  // y in {0,1}
  int t = threadIdx.x;
  __shared__ float ql[256];
  ql[t] = q[(size_t)m * INNER + h0 * HD + t];
  __syncthreads();
  if (t < 4) {
    float a = 0.f;
    const float* bc = bkp + (h0 + t) * HD;
    for (int c = 0; c < HD; c++) a += ql[t * HD + c] * bc[c];
    qbk[m * NH + h0 + t] = a;
  }
  for (int k = 0; k < 12; k++) {
    int idx = k * 256 + t;
    int hh = idx / DD;    // wave-uniform (768 % 256 == 0)
    int d = idx % DD;
    const float4* wrow = (const float4*)(Wk + (size_t)d * INNER + (h0 + hh) * HD);
    float acc = 0.f;
#pragma unroll
    for (int g4 = 0; g4 < 16; g4++) {
      float4 pk = wrow[g4];
      acc += ql[hh * HD + g4 * 4 + 0] * pk.x + ql[hh * HD + g4 * 4 + 1] * pk.y +
             ql[hh * HD + g4 * 4 + 2] * pk.z + ql[hh * HD + g4 * 4 + 3] * pk.w;
    }
    qm[(size_t)m * (NH * DD) + (size_t)(h0 + hh) * DD + d] = acc * mkp[(size_t)m * DD + d];
  }
}

// ------------- scores + softmax: w[m,h,v]  (4 heads per block) -------------
__global__ __launch_bounds__(256) void scores_kernel(
    const float* __restrict__ qm, const float* __restrict__ qbk,
    const float* __restrict__ s_ln, float* __restrict__ watt) {
  int m = blockIdx.x, h0 = blockIdx.y * 4, t = threadIdx.x;
  int b = m >> 6;
  __shared__ float ql[4 * DD];
  __shared__ float sc[4][256];
  for (int i = t; i < 4 * DD; i += 256)
    ql[i] = qm[(size_t)m * (NH * DD) + (size_t)h0 * DD + i];
  __syncthreads();
  float acc0 = 0.f, acc1 = 0.f, acc2 = 0.f, acc3 = 0.f;
  const float* srow = s_ln + (size_t)(b * VV + t) * DD;
#pragma unroll 2
  for (int d = 0; d < DD; d += 4) {
    float4 sv = *(const float4*)(srow + d);
    float4 q0 = *(const float4*)(ql + 0 * DD + d);
    float4 q1 = *(const float4*)(ql + 1 * DD + d);
    float4 q2 = *(const float4*)(ql + 2 * DD + d);
    float4 q3 = *(const float4*)(ql + 3 * DD + d);
    acc0 += q0.x * sv.x + q0.y * sv.y + q0.z * sv.z + q0.w * sv.w;
    acc1 += q1.x * sv.x + q1.y * sv.y + q1.z * sv.z + q1.w * sv.w;
    acc2 += q2.x * sv.x + q2.y * sv.y + q2.z * sv.z + q2.w * sv.w;
    acc3 += q3.x * sv.x + q3.y * sv.y + q3.z * sv.z + q3.w * sv.w;
  }
  sc[0][t] = (acc0 + qbk[m * NH + h0 + 0]) * 0.125f;
  sc[1][t] = (acc1 + qbk[m * NH + h0 + 1]) * 0.125f;
  sc[2][t] = (acc2 + qbk[m * NH + h0 + 2]) * 0.125f;
  sc[3][t] = (acc3 + qbk[m * NH + h0 + 3]) * 0.125f;
  __syncthreads();
  int wid = t >> 6, lane = t & 63;  // wave wid handles head h0+wid
  float x0 = sc[wid][lane], x1 = sc[wid][lane + 64];
  float x2 = sc[wid][lane + 128], x3 = sc[wid][lane + 192];
  float mx = fmaxf(fmaxf(x0, x1), fmaxf(x2, x3));
  for (int o = 1; o < 64; o <<= 1) mx = fmaxf(mx, __shfl_xor(mx, o, 64));
  float e0 = __expf(x0 - mx), e1 = __expf(x1 - mx);
  float e2 = __expf(x2 - mx), e3 = __expf(x3 - mx);
  float sm = e0 + e1 + e2 + e3;
  for (int o = 1; o < 64; o <<= 1) sm += __shfl_xor(sm, o, 64);
  float rinv = 1.0f / sm;
  float* wrow = watt + (size_t)m * (NH * VV) + (size_t)(h0 + wid) * VV;
  wrow[lane] = e0 * rinv; wrow[lane + 64] = e1 * rinv;
  wrow[lane + 128] = e2 * rinv; wrow[lane + 192] = e3 * rinv;
}

// ------- wsm[m,h,d] = mv[m,d] * Σ_v w[m,h,v]·s[b,v,d]  (d-chunked) --------
__global__ __launch_bounds__(256) void ws_gemm(
    const float* __restrict__ watt, const float* __restrict__ s_ln,
    const float* __restrict__ mvp, float* __restrict__ wsm) {
  int m = blockIdx.x, dc = blockIdx.y, t = threadIdx.x;
  int b = m >> 6;
  int d = dc * 256 + t;
  __shared__ float wl[NH * VV];
  for (int i = t; i < NH * VV; i += 256) wl[i] = watt[(size_t)m * (NH * VV) + i];
  __syncthreads();
  float acc[NH];
#pragma unroll
  for (int h = 0; h < NH; h++) acc[h] = 0.f;
  const float* sp = s_ln + (size_t)(b * VV) * DD + d;
#pragma unroll 4
  for (int v = 0; v < VV; v++) {
    float sv = sp[(size_t)v * DD];
#pragma unroll
    for (int h = 0; h < NH; h++) acc[h] += wl[h * VV + v] * sv;
  }
  float mvv = mvp[(size_t)m * DD + d];
#pragma unroll
  for (int h = 0; h < NH; h++)
    wsm[(size_t)m * (NH * DD) + (size_t)h * DD + d] = acc[h] * mvv;
}

// ------- mm[m,i] = me[m,i]*(Σ_d wsm[m,h(i),d]·Wv[d,i] + bv[i]) ------------
__global__ __launch_bounds__(256) void msg_kernel(
    const float* __restrict__ wsm, const float* __restrict__ Wv,
    const float* __restrict__ bv, const float* __restrict__ me,
    float* __restrict__ mm) {
  int m = blockIdx.x, cc = blockIdx.y, t = threadIdx.x;
  __shared__ float wl[4 * DD];
  for (int i = t; i < 4 * DD; i += 256)
    wl[i] = wsm[(size_t)m * (NH * DD) + (size_t)cc * (4 * DD) + i];
  __syncthreads();
  int i = cc * 256 + t;
  int hh = t >> 6;  // local head within loaded 4 (wave-uniform)
  float acc = 0.f;
  const float* wc = Wv + i;
#pragma unroll 8
  for (int d = 0; d < DD; d++) acc += wl[hh * DD + d] * wc[(size_t)d * INNER];
  mm[(size_t)m * INNER + i] = (acc + bv[i]) * me[(size_t)m * INNER + i];
}

// ------- out = rs + (mm @ We + be) * gamma  (2 rows, 256 cols / block) -----
__global__ __launch_bounds__(256) void out_kernel(
    const float* __restrict__ mm, const float* __restrict__ We,
    const float* __restrict__ be, const float* __restrict__ gamma,
    const float* __restrict__ rs, float* __restrict__ out) {
  int mg = blockIdx.x, cc = blockIdx.y, t = threadIdx.x;
  int m0 = mg * 2;
  __shared__ float ml[2][INNER];
  for (int i = t; i < 2 * INNER; i += 256) {
    int r = i >> 9, c = i & 511;
    ml[r][c] = mm[(size_t)(m0 + r) * INNER + c];
  }
  __syncthreads();
  int col = cc * 256 + t;
  const float* wc = We + col;
  float a0 = 0.f, a1 = 0.f;
#pragma unroll 8
  for (int i = 0; i < INNER; i++) {
    float wv = wc[(size_t)i * DD];
    a0 += ml[0][i] * wv; a1 += ml[1][i] * wv;
  }
  float bev = be[col], gv = gamma[col];
  out[(size_t)m0 * DD + col] = rs[(size_t)m0 * DD + col] + (a0 + bev) * gv;
  out[(size_t)(m0 + 1) * DD + col] =
      rs[(size_t)(m0 + 1) * DD + col] + (a1 + bev) * gv;
}

extern "C" void kernel_launch(void* const* d_in, const int* in_sizes, int n_in,
                              void* d_out, int out_size, void* d_ws, size_t ws_size,
                              hipStream_t stream) {
  const float* rs     = (const float*)d_in[0];
  const float* codes  = (const float*)d_in[1];
  const float* ss     = (const float*)d_in[2];
  const float* ln_r_g = (const float*)d_in[3];
  const float* ln_r_b = (const float*)d_in[4];
  const float* ln_s_g = (const float*)d_in[5];
  const float* ln_s_b = (const float*)d_in[6];
  const float* Wq  = (const float*)d_in[7];
  const float* bq  = (const float*)d_in[8];
  const float* Wmq = (const float*)d_in[9];
  const float* Wk  = (const float*)d_in[10];
  const float* bk  = (const float*)d_in[11];
  const float* Wmk = (const float*)d_in[12];
  const float* Wv  = (const float*)d_in[13];
  const float* bv  = (const float*)d_in[14];
  const float* Wmv = (const float*)d_in[15];
  const float* We  = (const float*)d_in[16];
  const float* be  = (const float*)d_in[17];
  const float* Wme = (const float*)d_in[18];
  const float* gamma = (const float*)d_in[19];

  float* ws   = (float*)d_ws;
  float* s_ln = ws;                    // 1024*768 = 786432
  float* r_ln = s_ln + 786432;         // 256*768  = 196608
  float* mq   = r_ln + 196608;         // 196608
  float* mk   = mq + 196608;           // 196608
  float* mv   = mk + 196608;           // 196608
  float* me   = mv + 196608;           // 256*512 = 131072
  float* q    = me + 131072;           // 131072
  float* qbk  = q + 131072;            // 256*8 = 2048
  float* qm   = qbk + 2048;            // 256*8*768 = 1572864
  float* watt = qm + 1572864;          // 256*8*256 = 524288
  float* wsm  = watt + 524288;         // 1572864
  float* mm   = wsm + 1572864;         // 131072
  // total ≈ 21.5 MiB of f32

  ln_kernel<<<dim3(BB * VV), 256, 0, stream>>>(ss, ln_s_g, ln_s_b, s_ln);
  ln_kernel<<<dim3(MM_ROWS), 256, 0, stream>>>(rs, ln_r_g, ln_r_b, r_ln);
  code_gemm<<<dim3(MM_ROWS / 4, 11), 256, 0, stream>>>(codes, Wmq, Wmk, Wmv, Wme,
                                                       mq, mk, mv, me);
  q_gemm<<<dim3(MM_ROWS / 2, 2), 256, 0, stream>>>(r_ln, mq, Wq, bq, q);
  qmk_kernel<<<dim3(MM_ROWS, 2), 256, 0, stream>>>(q, mk, Wk, bk, qm, qbk);
  scores_kernel<<<dim3(MM_ROWS, 2), 256, 0, stream>>>(qm, qbk, s_ln, watt);
  ws_gemm<<<dim3(MM_ROWS, 3), 256, 0, stream>>>(watt, s_ln, mv, wsm);
  msg_kernel<<<dim3(MM_ROWS, 2), 256, 0, stream>>>(wsm, Wv, bv, me, mm);
  out_kernel<<<dim3(MM_ROWS / 2, 3), 256, 0, stream>>>(mm, We, be, gamma, rs,
                                                       (float*)d_out);
}

// Round 4
// 396.933 us; speedup vs baseline: 1.0781x; 1.0781x over previous
//
#include <hip/hip_runtime.h>

// ReadInAttention — restructured f32 pipeline, GEMM-template kernels.
// Template: A-tile staged in LDS (wave-uniform broadcast reads), B streamed
// as coalesced float4 (1KB/wave-instr), each thread owns 4 cols x R rows.

#define DD 768
#define CDIM 384
#define NH 8
#define HD 64
#define INNER 512
#define MROWS 256   // B*U
#define VROWS 1024  // B*V
#define VV 256

__device__ __forceinline__ void fma4(float4& a, float s, const float4& b) {
  a.x += s * b.x; a.y += s * b.y; a.z += s * b.z; a.w += s * b.w;
}

// ---------- fused LayerNorm for sender (rows<1024) and receiver ----------
__global__ __launch_bounds__(256) void k_ln(
    const float* __restrict__ ss, const float* __restrict__ rs,
    const float* __restrict__ g_s, const float* __restrict__ b_s,
    const float* __restrict__ g_r, const float* __restrict__ b_r,
    float* __restrict__ s_ln, float* __restrict__ r_ln) {
  int row = blockIdx.x, t = threadIdx.x;
  const float *x, *g, *bb; float* y; int r;
  if (row < VROWS) { x = ss; g = g_s; bb = b_s; y = s_ln; r = row; }
  else             { x = rs; g = g_r; bb = b_r; y = r_ln; r = row - VROWS; }
  const float* xr = x + (size_t)r * DD;
  float v0 = xr[t], v1 = xr[t + 256], v2 = xr[t + 512];
  float s = v0 + v1 + v2;
  float sq = v0*v0 + v1*v1 + v2*v2;
  for (int o = 32; o > 0; o >>= 1) {
    s  += __shfl_down(s, o, 64);
    sq += __shfl_down(sq, o, 64);
  }
  __shared__ float red[8];
  int wid = t >> 6, lane = t & 63;
  if (lane == 0) { red[wid] = s; red[wid + 4] = sq; }
  __syncthreads();
  float sum = red[0] + red[1] + red[2] + red[3];
  float ssq = red[4] + red[5] + red[6] + red[7];
  float mu = sum * (1.0f / 768.0f);
  float var = ssq * (1.0f / 768.0f) - mu * mu;
  float rstd = rsqrtf(var + 1e-5f);
  float* yr = y + (size_t)r * DD;
  yr[t]       = (v0 - mu) * rstd * g[t]       + bb[t];
  yr[t + 256] = (v1 - mu) * rstd * g[t + 256] + bb[t + 256];
  yr[t + 512] = (v2 - mu) * rstd * g[t + 512] + bb[t + 512];
}

// ---------- transpose s_ln [b*256+v][d] -> sT [b][d][v] ----------
__global__ __launch_bounds__(256) void k_ts(const float* __restrict__ s_ln,
                                            float* __restrict__ sT) {
  __shared__ float TL[64 * 65];
  int v0 = blockIdx.x * 64, d0 = blockIdx.y * 64, b = blockIdx.z;
  int t = threadIdx.x, j = t & 63, i0 = t >> 6;
#pragma unroll
  for (int p = 0; p < 16; p++) {
    int i = p * 4 + i0;  // v index
    TL[i * 65 + j] = s_ln[(size_t)(b * VV + v0 + i) * DD + d0 + j];
  }
  __syncthreads();
#pragma unroll
  for (int p = 0; p < 16; p++) {
    int i = p * 4 + i0;  // d index
    sT[((size_t)b * DD + d0 + i) * VV + v0 + j] = TL[j * 65 + i];
  }
}

// ---------- transpose Wk [768][512] -> WkT [512][768] ----------
__global__ __launch_bounds__(256) void k_tw(const float* __restrict__ Wk,
                                            float* __restrict__ WkT) {
  __shared__ float TL[64 * 65];
  int d0 = blockIdx.x * 64, c0 = blockIdx.y * 64;
  int t = threadIdx.x, j = t & 63, i0 = t >> 6;
#pragma unroll
  for (int p = 0; p < 16; p++) {
    int i = p * 4 + i0;  // d index
    TL[i * 65 + j] = Wk[(size_t)(d0 + i) * INNER + c0 + j];
  }
  __syncthreads();
#pragma unroll
  for (int p = 0; p < 16; p++) {
    int i = p * 4 + i0;  // c index
    WkT[(size_t)(c0 + i) * DD + d0 + j] = TL[j * 65 + i];
  }
}

// ---------- m* = 1 + codes @ Wm*  (tile 8 rows x 256 cols, R=2) ----------
__global__ __launch_bounds__(256) void k_code(
    const float* __restrict__ codes, const float* __restrict__ Wmq,
    const float* __restrict__ Wmk, const float* __restrict__ Wmv,
    const float* __restrict__ Wme, float* __restrict__ mq,
    float* __restrict__ mk, float* __restrict__ mv, float* __restrict__ me) {
  int mb = blockIdx.x, cc = blockIdx.y, t = threadIdx.x;
  const float* W; float* outp; int N, col0;
  if (cc < 3)      { W = Wmq; outp = mq; N = DD;    col0 = cc * 256; }
  else if (cc < 6) { W = Wmk; outp = mk; N = DD;    col0 = (cc - 3) * 256; }
  else if (cc < 9) { W = Wmv; outp = mv; N = DD;    col0 = (cc - 6) * 256; }
  else             { W = Wme; outp = me; N = INNER; col0 = (cc - 9) * 256; }
  __shared__ float AL[8 * CDIM];
  int m0 = mb * 8, kl = t & 63, rg = t >> 6;
#pragma unroll
  for (int p = 0; p < 2; p++)
#pragma unroll
    for (int kb = 0; kb < 6; kb++) {
      int r = p * 4 + rg, k = kb * 64 + kl;
      AL[r * CDIM + k] = codes[(size_t)(m0 + r) * CDIM + k];
    }
  __syncthreads();
  int col = col0 + 4 * kl;
  const float* Bp = W + col;
  float4 a0 = {0,0,0,0}, a1 = {0,0,0,0};
  const float* A0 = AL + (rg * 2 + 0) * CDIM;
  const float* A1 = AL + (rg * 2 + 1) * CDIM;
#pragma unroll 4
  for (int k = 0; k < CDIM; k++) {
    float4 bv = *(const float4*)Bp; Bp += N;
    fma4(a0, A0[k], bv); fma4(a1, A1[k], bv);
  }
  int m = m0 + rg * 2;
  float4 o0 = {1.0f + a0.x, 1.0f + a0.y, 1.0f + a0.z, 1.0f + a0.w};
  float4 o1 = {1.0f + a1.x, 1.0f + a1.y, 1.0f + a1.z, 1.0f + a1.w};
  *(float4*)(outp + (size_t)m * N + col) = o0;
  *(float4*)(outp + (size_t)(m + 1) * N + col) = o1;
}

// ---------- q = (r_ln*mq) @ Wq + bq  (tile 4 rows x 256 cols, R=1) ----------
__global__ __launch_bounds__(256) void k_q(
    const float* __restrict__ r_ln, const float* __restrict__ mq,
    const float* __restrict__ Wq, const float* __restrict__ bq,
    float* __restrict__ q) {
  int mb = blockIdx.x, ccy = blockIdx.y, t = threadIdx.x;
  __shared__ float AL[4 * DD];
  int m0 = mb * 4, kl = t & 63, rg = t >> 6;
#pragma unroll
  for (int kb = 0; kb < 12; kb++) {
    int k = kb * 64 + kl;
    AL[rg * DD + k] = r_ln[(size_t)(m0 + rg) * DD + k] *
                      mq[(size_t)(m0 + rg) * DD + k];
  }
  __syncthreads();
  int col = ccy * 256 + 4 * kl;
  const float* Bp = Wq + col;
  float4 a = {0,0,0,0};
  const float* A0 = AL + rg * DD;
#pragma unroll 4
  for (int k = 0; k < DD; k++) {
    float4 bv = *(const float4*)Bp; Bp += INNER;
    fma4(a, A0[k], bv);
  }
  float4 bb = *(const float4*)(bq + col);
  float4 o = {a.x + bb.x, a.y + bb.y, a.z + bb.z, a.w + bb.w};
  *(float4*)(q + (size_t)(m0 + rg) * INNER + col) = o;
}

// ---------- qbk[m,h] = sum_c q[m,h*64+c]*bk[h*64+c]  (1 wave per m) --------
__global__ __launch_bounds__(64) void k_qbk(const float* __restrict__ q,
                                            const float* __restrict__ bk,
                                            float* __restrict__ qbk) {
  int m = blockIdx.x, lane = threadIdx.x;
#pragma unroll
  for (int h = 0; h < NH; h++) {
    float v = q[(size_t)m * INNER + h * HD + lane] * bk[h * HD + lane];
    for (int o = 32; o > 0; o >>= 1) v += __shfl_xor(v, o, 64);
    if (lane == 0) qbk[m * NH + h] = v;
  }
}

// ---------- qm[(m*8+h)][d] = mk[m,d]*sum_c q[m,hc]*WkT[hc][d]  R=2 ----------
__global__ __launch_bounds__(256) void k_qmk(
    const float* __restrict__ q, const float* __restrict__ WkT,
    const float* __restrict__ mk, float* __restrict__ qm) {
  int mb = blockIdx.x, dc = blockIdx.y, h = blockIdx.z, t = threadIdx.x;
  __shared__ float AL[8 * HD];
  int m0 = mb * 8, kl = t & 63, rg = t >> 6;
#pragma unroll
  for (int p = 0; p < 2; p++) {
    int r = p * 4 + rg;
    AL[r * HD + kl] = q[(size_t)(m0 + r) * INNER + h * HD + kl];
  }
  __syncthreads();
  int col = dc * 256 + 4 * kl;
  const float* Bp = WkT + (size_t)(h * HD) * DD + col;
  float4 a0 = {0,0,0,0}, a1 = {0,0,0,0};
  const float* A0 = AL + (rg * 2) * HD;
  const float* A1 = A0 + HD;
#pragma unroll 4
  for (int k = 0; k < HD; k++) {
    float4 bv = *(const float4*)Bp; Bp += DD;
    fma4(a0, A0[k], bv); fma4(a1, A1[k], bv);
  }
  int m = m0 + rg * 2;
  float4 k0 = *(const float4*)(mk + (size_t)m * DD + col);
  float4 k1 = *(const float4*)(mk + (size_t)(m + 1) * DD + col);
  float4 o0 = {a0.x * k0.x, a0.y * k0.y, a0.z * k0.z, a0.w * k0.w};
  float4 o1 = {a1.x * k1.x, a1.y * k1.y, a1.z * k1.z, a1.w * k1.w};
  *(float4*)(qm + ((size_t)m * NH + h) * DD + col) = o0;
  *(float4*)(qm + ((size_t)(m + 1) * NH + h) * DD + col) = o1;
}

// ---------- scores + softmax fused. Per b: [512 x 768] x sT_b [768 x 256] --
// tile 8 rows x 256 cols (R=2); each wave owns 2 full rows -> softmax inline.
__global__ __launch_bounds__(256) void k_scores(
    const float* __restrict__ qm, const float* __restrict__ qbk,
    const float* __restrict__ sT, float* __restrict__ watt) {
  int mb = blockIdx.x, b = blockIdx.y, t = threadIdx.x;
  __shared__ float AL[8 * DD];
  int m0 = mb * 8, kl = t & 63, rg = t >> 6;
#pragma unroll
  for (int p = 0; p < 2; p++)
#pragma unroll
    for (int kb = 0; kb < 12; kb++) {
      int r = p * 4 + rg, k = kb * 64 + kl;
      AL[r * DD + k] = qm[(size_t)(b * 512 + m0 + r) * DD + k];
    }
  __syncthreads();
  int col = 4 * kl;
  const float* Bp = sT + (size_t)b * DD * VV + col;
  float4 a0 = {0,0,0,0}, a1 = {0,0,0,0};
  const float* A0 = AL + (rg * 2) * DD;
  const float* A1 = A0 + DD;
#pragma unroll 4
  for (int k = 0; k < DD; k++) {
    float4 bv = *(const float4*)Bp; Bp += VV;
    fma4(a0, A0[k], bv); fma4(a1, A1[k], bv);
  }
  // softmax per row (each wave owns rows gi0, gi0+1 entirely: 64 lanes x 4)
#pragma unroll
  for (int j = 0; j < 2; j++) {
    float4 a = (j == 0) ? a0 : a1;
    int gi = b * 512 + m0 + rg * 2 + j;
    float qb = qbk[gi];
    float x0 = (a.x + qb) * 0.125f, x1 = (a.y + qb) * 0.125f;
    float x2 = (a.z + qb) * 0.125f, x3 = (a.w + qb) * 0.125f;
    float mx = fmaxf(fmaxf(x0, x1), fmaxf(x2, x3));
    for (int o = 1; o < 64; o <<= 1) mx = fmaxf(mx, __shfl_xor(mx, o, 64));
    float e0 = __expf(x0 - mx), e1 = __expf(x1 - mx);
    float e2 = __expf(x2 - mx), e3 = __expf(x3 - mx);
    float sm = e0 + e1 + e2 + e3;
    for (int o = 1; o < 64; o <<= 1) sm += __shfl_xor(sm, o, 64);
    float rinv = 1.0f / sm;
    float4 o4 = {e0 * rinv, e1 * rinv, e2 * rinv, e3 * rinv};
    *(float4*)(watt + (size_t)gi * VV + col) = o4;
  }
}

// ---------- wsm[h][m][d] = mv[m,d]*sum_v watt[(u,h)][v]*s_ln[b,v,d]  R=4 ---
__global__ __launch_bounds__(256) void k_ws(
    const float* __restrict__ watt, const float* __restrict__ s_ln,
    const float* __restrict__ mvp, float* __restrict__ wsm) {
  int mb = blockIdx.x, dc = blockIdx.y, b = blockIdx.z, t = threadIdx.x;
  __shared__ float AL[16 * VV];
  int m0 = mb * 16, kl = t & 63, rg = t >> 6;
#pragma unroll
  for (int p = 0; p < 16; p++) {
    int idx = p * 256 + t, r = idx >> 8, c = idx & 255;
    AL[idx] = watt[(size_t)(b * 512 + m0 + r) * VV + c];
  }
  __syncthreads();
  int col = dc * 256 + 4 * kl;
  const float* Bp = s_ln + (size_t)(b * VV) * DD + col;
  float4 a0 = {0,0,0,0}, a1 = {0,0,0,0}, a2 = {0,0,0,0}, a3 = {0,0,0,0};
  const float* A0 = AL + (rg * 4) * VV;
#pragma unroll 2
  for (int k = 0; k < VV; k++) {
    float4 bv = *(const float4*)Bp; Bp += DD;
    fma4(a0, A0[k], bv); fma4(a1, A0[VV + k], bv);
    fma4(a2, A0[2 * VV + k], bv); fma4(a3, A0[3 * VV + k], bv);
  }
#pragma unroll
  for (int j = 0; j < 4; j++) {
    float4 a = (j == 0) ? a0 : (j == 1) ? a1 : (j == 2) ? a2 : a3;
    int lr = m0 + rg * 4 + j;            // 0..511 = u*8+h
    int u = lr >> 3, h = lr & 7, m = b * 64 + u;
    float4 mv4 = *(const float4*)(mvp + (size_t)m * DD + col);
    float4 o = {a.x * mv4.x, a.y * mv4.y, a.z * mv4.z, a.w * mv4.w};
    *(float4*)(wsm + ((size_t)h * MROWS + m) * DD + col) = o;
  }
}

// ---------- mm[m][h*64+c] = me*(sum_d wsm[h][m][d]*Wv[d][h*64+c] + bv) -----
// block: 16 rows x 64 cols of head h; rowgrp = t>>4 (padded LDS stride 772)
__global__ __launch_bounds__(256) void k_msg(
    const float* __restrict__ wsm, const float* __restrict__ Wv,
    const float* __restrict__ bv, const float* __restrict__ me,
    float* __restrict__ mm) {
  int mb = blockIdx.x, h = blockIdx.y, t = threadIdx.x;
  __shared__ float AL[16 * 772];
  int m0 = mb * 16, kl = t & 63, rg4 = t >> 6;
#pragma unroll
  for (int rl = 0; rl < 4; rl++)
#pragma unroll
    for (int kb = 0; kb < 12; kb++) {
      int r = rl * 4 + rg4, k = kb * 64 + kl;
      AL[r * 772 + k] = wsm[((size_t)h * MROWS + m0 + r) * DD + k];
    }
  __syncthreads();
  int cg = t & 15, row = t >> 4;
  int icol = h * HD + 4 * cg;
  const float* Bp = Wv + icol;
  const float* A0 = AL + row * 772;
  float4 a = {0,0,0,0};
#pragma unroll 4
  for (int k = 0; k < DD; k++) {
    float4 bvv = *(const float4*)Bp; Bp += INNER;
    fma4(a, A0[k], bvv);
  }
  int m = m0 + row;
  float4 b4 = *(const float4*)(bv + icol);
  float4 me4 = *(const float4*)(me + (size_t)m * INNER + icol);
  float4 o = {(a.x + b4.x) * me4.x, (a.y + b4.y) * me4.y,
              (a.z + b4.z) * me4.z, (a.w + b4.w) * me4.w};
  *(float4*)(mm + (size_t)m * INNER + icol) = o;
}

// ---------- out = rs + (mm @ We + be)*gamma  (tile 4 rows x 256, R=1) ------
__global__ __launch_bounds__(256) void k_out(
    const float* __restrict__ mm, const float* __restrict__ We,
    const float* __restrict__ be, const float* __restrict__ gamma,
    const float* __restrict__ rs, float* __restrict__ outp) {
  int mb = blockIdx.x, dc = blockIdx.y, t = threadIdx.x;
  __shared__ float AL[4 * INNER];
  int m0 = mb * 4, kl = t & 63, rg = t >> 6;
#pragma unroll
  for (int kb = 0; kb < 8; kb++) {
    int k = kb * 64 + kl;
    AL[rg * INNER + k] = mm[(size_t)(m0 + rg) * INNER + k];
  }
  __syncthreads();
  int col = dc * 256 + 4 * kl;
  const float* Bp = We + col;
  const float* A0 = AL + rg * INNER;
  float4 a = {0,0,0,0};
#pragma unroll 4
  for (int k = 0; k < INNER; k++) {
    float4 bv = *(const float4*)Bp; Bp += DD;
    fma4(a, A0[k], bv);
  }
  float4 be4 = *(const float4*)(be + col);
  float4 g4 = *(const float4*)(gamma + col);
  float4 rs4 = *(const float4*)(rs + (size_t)(m0 + rg) * DD + col);
  float4 o = {rs4.x + (a.x + be4.x) * g4.x, rs4.y + (a.y + be4.y) * g4.y,
              rs4.z + (a.z + be4.z) * g4.z, rs4.w + (a.w + be4.w) * g4.w};
  *(float4*)(outp + (size_t)(m0 + rg) * DD + col) = o;
}

extern "C" void kernel_launch(void* const* d_in, const int* in_sizes, int n_in,
                              void* d_out, int out_size, void* d_ws, size_t ws_size,
                              hipStream_t stream) {
  const float* rs     = (const float*)d_in[0];
  const float* codes  = (const float*)d_in[1];
  const float* ss     = (const float*)d_in[2];
  const float* ln_r_g = (const float*)d_in[3];
  const float* ln_r_b = (const float*)d_in[4];
  const float* ln_s_g = (const float*)d_in[5];
  const float* ln_s_b = (const float*)d_in[6];
  const float* Wq  = (const float*)d_in[7];
  const float* bq  = (const float*)d_in[8];
  const float* Wmq = (const float*)d_in[9];
  const float* Wk  = (const float*)d_in[10];
  const float* bk  = (const float*)d_in[11];
  const float* Wmk = (const float*)d_in[12];
  const float* Wv  = (const float*)d_in[13];
  const float* bv  = (const float*)d_in[14];
  const float* Wmv = (const float*)d_in[15];
  const float* We  = (const float*)d_in[16];
  const float* be  = (const float*)d_in[17];
  const float* Wme = (const float*)d_in[18];
  const float* gamma = (const float*)d_in[19];

  float* w    = (float*)d_ws;
  float* s_ln = w;                      // 786432
  float* r_ln = s_ln + 786432;          // 196608
  float* sT   = r_ln + 196608;          // 786432
  float* WkT  = sT + 786432;            // 393216
  float* mq   = WkT + 393216;           // 196608
  float* mk   = mq + 196608;            // 196608
  float* mv   = mk + 196608;            // 196608
  float* me   = mv + 196608;            // 131072
  float* q    = me + 131072;            // 131072
  float* qbk  = q + 131072;             // 2048
  float* qm   = qbk + 2048;             // 1572864
  float* watt = qm + 1572864;           // 524288
  float* mm   = watt + 524288;          // 131072
  float* wsm  = qm;                     // alias: qm dead after k_scores
  // total ~21.0 MB

  k_ln<<<dim3(VROWS + MROWS), 256, 0, stream>>>(ss, rs, ln_s_g, ln_s_b,
                                                ln_r_g, ln_r_b, s_ln, r_ln);
  k_ts<<<dim3(4, 12, 4), 256, 0, stream>>>(s_ln, sT);
  k_tw<<<dim3(12, 8), 256, 0, stream>>>(Wk, WkT);
  k_code<<<dim3(32, 11), 256, 0, stream>>>(codes, Wmq, Wmk, Wmv, Wme,
                                           mq, mk, mv, me);
  k_q<<<dim3(64, 2), 256, 0, stream>>>(r_ln, mq, Wq, bq, q);
  k_qbk<<<dim3(MROWS), 64, 0, stream>>>(q, bk, qbk);
  k_qmk<<<dim3(32, 3, 8), 256, 0, stream>>>(q, WkT, mk, qm);
  k_scores<<<dim3(64, 4), 256, 0, stream>>>(qm, qbk, sT, watt);
  k_ws<<<dim3(32, 3, 4), 256, 0, stream>>>(watt, s_ln, mv, wsm);
  k_msg<<<dim3(16, 8), 256, 0, stream>>>(wsm, Wv, bv, me, mm);
  k_out<<<dim3(64, 3), 256, 0, stream>>>(mm, We, be, gamma, rs, (float*)d_out);
}

// Round 5
// 284.665 us; speedup vs baseline: 1.5034x; 1.3944x over previous
//
#include <hip/hip_runtime.h>

// ReadInAttention — 8-stage latency-optimized f32 pipeline.
// All long-K GEMMs are k-split into 2 partial buffers (consumers sum at
// A-tile load). Blocks: 8 rows x 128/256 cols; B streamed coalesced
// float2/float4; A staged in LDS (broadcast reads). Epilogues (bias, 1+,
// modulation, softmax) folded into consumers.

#define DD 768
#define CDIM 384
#define NH 8
#define HD 64
#define INNER 512
#define VV 256

__device__ __forceinline__ void fma4(float4& a, float s, const float4& b) {
  a.x += s * b.x; a.y += s * b.y; a.z += s * b.z; a.w += s * b.w;
}
__device__ __forceinline__ void fma2(float2& a, float s, const float2& b) {
  a.x += s * b.x; a.y += s * b.y;
}

// =================== Stage 1: LN (1280) | code GEMM (704) | WkT (96) =======
__global__ __launch_bounds__(256) void k_s1(
    const float* __restrict__ ss, const float* __restrict__ rs,
    const float* __restrict__ g_s, const float* __restrict__ b_s,
    const float* __restrict__ g_r, const float* __restrict__ b_r,
    const float* __restrict__ codes, const float* __restrict__ Wmq,
    const float* __restrict__ Wmk, const float* __restrict__ Wmv,
    const float* __restrict__ Wme, const float* __restrict__ Wk,
    float* __restrict__ s_ln, float* __restrict__ r_ln,
    float* __restrict__ mq, float* __restrict__ mk, float* __restrict__ mv,
    float* __restrict__ me, float* __restrict__ WkT) {
  __shared__ float SB[4160];
  int bid = blockIdx.x, t = threadIdx.x;
  if (bid < 1280) {            // ---- LayerNorm, one row per block ----
    const float *x, *g, *bb; float* y; int r;
    if (bid < 1024) { x = ss; g = g_s; bb = b_s; y = s_ln; r = bid; }
    else            { x = rs; g = g_r; bb = b_r; y = r_ln; r = bid - 1024; }
    const float* xr = x + (size_t)r * DD;
    float v0 = xr[t], v1 = xr[t + 256], v2 = xr[t + 512];
    float s = v0 + v1 + v2, sq = v0*v0 + v1*v1 + v2*v2;
    for (int o = 32; o > 0; o >>= 1) {
      s += __shfl_down(s, o, 64); sq += __shfl_down(sq, o, 64);
    }
    int wid = t >> 6, lane = t & 63;
    if (lane == 0) { SB[wid] = s; SB[wid + 4] = sq; }
    __syncthreads();
    float sum = SB[0] + SB[1] + SB[2] + SB[3];
    float ssq = SB[4] + SB[5] + SB[6] + SB[7];
    float mu = sum * (1.0f / 768.0f);
    float var = ssq * (1.0f / 768.0f) - mu * mu;
    float rstd = rsqrtf(var + 1e-5f);
    float* yr = y + (size_t)r * DD;
    yr[t]       = (v0 - mu) * rstd * g[t]       + bb[t];
    yr[t + 256] = (v1 - mu) * rstd * g[t + 256] + bb[t + 256];
    yr[t + 512] = (v2 - mu) * rstd * g[t + 512] + bb[t + 512];
  } else if (bid < 1984) {     // ---- code GEMM: 8 rows x 128 cols, K=384 ----
    int cc = bid - 1280;
    int mb = cc / 22, nc = cc % 22;
    int base = nc * 128;
    const float* W; float* outp; int N, colW;
    if (base < 768)       { W = Wmq; outp = mq; N = DD;    colW = base; }
    else if (base < 1536) { W = Wmk; outp = mk; N = DD;    colW = base - 768; }
    else if (base < 2304) { W = Wmv; outp = mv; N = DD;    colW = base - 1536; }
    else                  { W = Wme; outp = me; N = INNER; colW = base - 2304; }
    int m0 = mb * 8;
    float* AL = SB;
#pragma unroll
    for (int p = 0; p < 12; p++) {
      int idx = p * 256 + t, r = idx / CDIM, k = idx % CDIM;
      AL[idx] = codes[(size_t)(m0 + r) * CDIM + k];
    }
    __syncthreads();
    int kl = t & 63, rg = t >> 6;
    int col = colW + 2 * kl;
    const float* Bp = W + col;
    const float* A0 = AL + (rg * 2) * CDIM;
    const float* A1 = A0 + CDIM;
    float2 a0 = {0, 0}, a1 = {0, 0};
#pragma unroll 4
    for (int k = 0; k < CDIM; k++) {
      float2 bv = *(const float2*)Bp; Bp += N;
      fma2(a0, A0[k], bv); fma2(a1, A1[k], bv);
    }
    int m = m0 + rg * 2;
    float2 o0 = {1.0f + a0.x, 1.0f + a0.y};
    float2 o1 = {1.0f + a1.x, 1.0f + a1.y};
    *(float2*)(outp + (size_t)m * N + col) = o0;
    *(float2*)(outp + (size_t)(m + 1) * N + col) = o1;
  } else {                     // ---- Wk transpose 768x512 -> 512x768 ----
    int tid = bid - 1984;
    int d0 = (tid >> 3) * 64, c0 = (tid & 7) * 64;
    int j = t & 63, i0 = t >> 6;
#pragma unroll
    for (int p = 0; p < 16; p++) {
      int i = p * 4 + i0;
      SB[i * 65 + j] = Wk[(size_t)(d0 + i) * INNER + c0 + j];
    }
    __syncthreads();
#pragma unroll
    for (int p = 0; p < 16; p++) {
      int i = p * 4 + i0;
      WkT[(size_t)(c0 + i) * DD + d0 + j] = SB[j * 65 + i];
    }
  }
}

// ========== Stage 2: s transpose (192) | q partial GEMM (256) ==============
__global__ __launch_bounds__(256) void k_s2(
    const float* __restrict__ s_ln, const float* __restrict__ r_ln,
    const float* __restrict__ mq, const float* __restrict__ Wq,
    float* __restrict__ sT, float* __restrict__ qp) {
  __shared__ float SB[4160];
  int bid = blockIdx.x, t = threadIdx.x;
  if (bid < 192) {             // ---- sT[b][d][v] ----
    int vt = bid & 3, dt = (bid >> 2) % 12, b = bid / 48;
    int v0 = vt * 64, d0 = dt * 64;
    int j = t & 63, i0 = t >> 6;
#pragma unroll
    for (int p = 0; p < 16; p++) {
      int i = p * 4 + i0;
      SB[i * 65 + j] = s_ln[(size_t)(b * VV + v0 + i) * DD + d0 + j];
    }
    __syncthreads();
#pragma unroll
    for (int p = 0; p < 16; p++) {
      int i = p * 4 + i0;
      sT[((size_t)b * DD + d0 + i) * VV + v0 + j] = SB[j * 65 + i];
    }
  } else {                     // ---- q partial: 8 rows x 128 cols, Kc=384 ---
    int cc = bid - 192;
    int mb = cc >> 3, rem = cc & 7, nc = rem >> 1, ks = rem & 1;
    int m0 = mb * 8, col0 = nc * 128, k0 = ks * 384;
    float* AL = SB;
#pragma unroll
    for (int p = 0; p < 12; p++) {
      int idx = p * 256 + t, r = idx / 384, k = idx % 384;
      size_t off = (size_t)(m0 + r) * DD + k0 + k;
      AL[idx] = r_ln[off] * mq[off];
    }
    __syncthreads();
    int kl = t & 63, rg = t >> 6;
    int col = col0 + 2 * kl;
    const float* Bp = Wq + (size_t)k0 * INNER + col;
    const float* A0 = AL + (rg * 2) * 384;
    const float* A1 = A0 + 384;
    float2 a0 = {0, 0}, a1 = {0, 0};
#pragma unroll 4
    for (int k = 0; k < 384; k++) {
      float2 bv = *(const float2*)Bp; Bp += INNER;
      fma2(a0, A0[k], bv); fma2(a1, A1[k], bv);
    }
    int m = m0 + rg * 2;
    float* dst = qp + (size_t)ks * (256 * INNER);
    *(float2*)(dst + (size_t)m * INNER + col) = a0;
    *(float2*)(dst + (size_t)(m + 1) * INNER + col) = a1;
  }
}

// ========== Stage 3: qmk (768) | qbk (256) =================================
__global__ __launch_bounds__(256) void k_s3(
    const float* __restrict__ qp, const float* __restrict__ bq,
    const float* __restrict__ WkT, const float* __restrict__ mk,
    const float* __restrict__ bk, float* __restrict__ qm,
    float* __restrict__ qbk) {
  __shared__ float SB[640];
  int bid = blockIdx.x, t = threadIdx.x;
  const float* qp0 = qp;
  const float* qp1 = qp + 256 * INNER;
  if (bid < 768) {             // ---- qm: head h, 8 rows x 256 d-cols, K=64 --
    int mb = bid / 24, r24 = bid % 24, dc = r24 >> 3, h = r24 & 7;
    int m0 = mb * 8;
    float* AL = SB;
#pragma unroll
    for (int p = 0; p < 2; p++) {
      int idx = p * 256 + t, r = idx >> 6, c = idx & 63;
      int i = h * HD + c;
      AL[idx] = qp0[(size_t)(m0 + r) * INNER + i] +
                qp1[(size_t)(m0 + r) * INNER + i] + bq[i];
    }
    __syncthreads();
    int kl = t & 63, rg = t >> 6;
    int col = dc * 256 + 4 * kl;
    const float* Bp = WkT + (size_t)(h * HD) * DD + col;
    const float* A0 = AL + (rg * 2) * HD;
    const float* A1 = A0 + HD;
    float4 a0 = {0, 0, 0, 0}, a1 = {0, 0, 0, 0};
#pragma unroll 4
    for (int k = 0; k < HD; k++) {
      float4 bv = *(const float4*)Bp; Bp += DD;
      fma4(a0, A0[k], bv); fma4(a1, A1[k], bv);
    }
    int m = m0 + rg * 2;
    float4 k0v = *(const float4*)(mk + (size_t)m * DD + col);
    float4 k1v = *(const float4*)(mk + (size_t)(m + 1) * DD + col);
    float4 o0 = {a0.x * k0v.x, a0.y * k0v.y, a0.z * k0v.z, a0.w * k0v.w};
    float4 o1 = {a1.x * k1v.x, a1.y * k1v.y, a1.z * k1v.z, a1.w * k1v.w};
    *(float4*)(qm + ((size_t)m * NH + h) * DD + col) = o0;
    *(float4*)(qm + ((size_t)(m + 1) * NH + h) * DD + col) = o1;
  } else {                     // ---- qbk[m][h] ----
    int m = bid - 768;
    int i = t, i2 = t + 256;
    SB[i]  = (qp0[(size_t)m * INNER + i]  + qp1[(size_t)m * INNER + i]  + bq[i])  * bk[i];
    SB[i2] = (qp0[(size_t)m * INNER + i2] + qp1[(size_t)m * INNER + i2] + bq[i2]) * bk[i2];
    __syncthreads();
    if (t < 8) {
      float a = 0.f;
      for (int c = 0; c < HD; c++) a += SB[t * HD + c];
      qbk[m * NH + t] = a;
    }
  }
}

// ========== Stage 4: scores partial (512) ==================================
__global__ __launch_bounds__(256) void k_s4(
    const float* __restrict__ qm, const float* __restrict__ sT,
    float* __restrict__ scp) {
  __shared__ float AL[3072];
  int bid = blockIdx.x, t = threadIdx.x;
  int ks = bid & 1, b = (bid >> 1) & 3, mb = bid >> 3;
  int gi0 = b * 512 + mb * 8, k0 = ks * 384;
#pragma unroll
  for (int p = 0; p < 12; p++) {
    int idx = p * 256 + t, r = idx / 384, k = idx % 384;
    AL[idx] = qm[(size_t)(gi0 + r) * DD + k0 + k];
  }
  __syncthreads();
  int kl = t & 63, rg = t >> 6;
  int col = 4 * kl;
  const float* Bp = sT + ((size_t)b * DD + k0) * VV + col;
  const float* A0 = AL + (rg * 2) * 384;
  const float* A1 = A0 + 384;
  float4 a0 = {0, 0, 0, 0}, a1 = {0, 0, 0, 0};
#pragma unroll 4
  for (int k = 0; k < 384; k++) {
    float4 bv = *(const float4*)Bp; Bp += VV;
    fma4(a0, A0[k], bv); fma4(a1, A1[k], bv);
  }
  int gi = gi0 + rg * 2;
  float* dst = scp + (size_t)ks * (2048 * VV);
  *(float4*)(dst + (size_t)gi * VV + col) = a0;
  *(float4*)(dst + (size_t)(gi + 1) * VV + col) = a1;
}

// ========== Stage 5: softmax + ws GEMM (768) ===============================
__global__ __launch_bounds__(256) void k_s5(
    const float* __restrict__ scp, const float* __restrict__ qbk,
    const float* __restrict__ s_ln, const float* __restrict__ mvp,
    float* __restrict__ wsm) {
  __shared__ float SC[2048];
  int bid = blockIdx.x, t = threadIdx.x;
  int b = bid & 3, u = (bid >> 2) & 63, dc = bid >> 8;
  int m = b * 64 + u, gi0 = b * 512 + u * 8;
  const float* sc0 = scp;
  const float* sc1 = scp + 2048 * VV;
#pragma unroll
  for (int p = 0; p < 8; p++) {
    int idx = p * 256 + t, r = idx >> 8, c = idx & 255;
    float raw = sc0[(size_t)(gi0 + r) * VV + c] + sc1[(size_t)(gi0 + r) * VV + c];
    SC[idx] = (raw + qbk[m * NH + r]) * 0.125f;
  }
  __syncthreads();
  int wid = t >> 6, lane = t & 63;
#pragma unroll
  for (int j = 0; j < 2; j++) {
    int h = wid * 2 + j;
    float x0 = SC[h * 256 + lane],        x1 = SC[h * 256 + lane + 64];
    float x2 = SC[h * 256 + lane + 128],  x3 = SC[h * 256 + lane + 192];
    float mx = fmaxf(fmaxf(x0, x1), fmaxf(x2, x3));
    for (int o = 1; o < 64; o <<= 1) mx = fmaxf(mx, __shfl_xor(mx, o, 64));
    float e0 = __expf(x0 - mx), e1 = __expf(x1 - mx);
    float e2 = __expf(x2 - mx), e3 = __expf(x3 - mx);
    float sm = e0 + e1 + e2 + e3;
    for (int o = 1; o < 64; o <<= 1) sm += __shfl_xor(sm, o, 64);
    float rinv = 1.0f / sm;
    SC[h * 256 + lane] = e0 * rinv;       SC[h * 256 + lane + 64] = e1 * rinv;
    SC[h * 256 + lane + 128] = e2 * rinv; SC[h * 256 + lane + 192] = e3 * rinv;
  }
  __syncthreads();
  int kl = t & 63, rg = t >> 6;
  int col = dc * 256 + 4 * kl;
  const float* Bp = s_ln + (size_t)(b * VV) * DD + col;
  const float* A0 = SC + (rg * 2) * 256;
  const float* A1 = A0 + 256;
  float4 a0 = {0, 0, 0, 0}, a1 = {0, 0, 0, 0};
#pragma unroll 4
  for (int v = 0; v < VV; v++) {
    float4 bv = *(const float4*)Bp; Bp += DD;
    fma4(a0, A0[v], bv); fma4(a1, A1[v], bv);
  }
  float4 mv4 = *(const float4*)(mvp + (size_t)m * DD + col);
  float4 o0 = {a0.x * mv4.x, a0.y * mv4.y, a0.z * mv4.z, a0.w * mv4.w};
  float4 o1 = {a1.x * mv4.x, a1.y * mv4.y, a1.z * mv4.z, a1.w * mv4.w};
  int h0 = rg * 2;
  *(float4*)(wsm + ((size_t)h0 * 256 + m) * DD + col) = o0;
  *(float4*)(wsm + ((size_t)(h0 + 1) * 256 + m) * DD + col) = o1;
}

// ========== Stage 6: msg partial (256) =====================================
__global__ __launch_bounds__(256) void k_s6(
    const float* __restrict__ wsm, const float* __restrict__ Wv,
    float* __restrict__ mmp) {
  __shared__ float AL[6144];
  int bid = blockIdx.x, t = threadIdx.x;
  int ks = bid & 1, hp = (bid >> 1) & 3, mb = bid >> 3;
  int h0 = hp * 2, m0 = mb * 8, k0 = ks * 384;
#pragma unroll
  for (int p = 0; p < 24; p++) {
    int idx = p * 256 + t;
    int e = idx / 3072, rem = idx % 3072, r = rem / 384, k = rem % 384;
    AL[idx] = wsm[((size_t)(h0 + e) * 256 + m0 + r) * DD + k0 + k];
  }
  __syncthreads();
  int kl = t & 63, rg = t >> 6;
  int jc = 2 * kl;                 // 0..126 within 128-col (2-head) strip
  int head_sel = kl >> 5;
  int col = h0 * HD + jc;          // global Wv col
  const float* Bp = Wv + (size_t)k0 * INNER + col;
  const float* A0 = AL + head_sel * 3072 + (rg * 2) * 384;
  const float* A1 = A0 + 384;
  float2 a0 = {0, 0}, a1 = {0, 0};
#pragma unroll 4
  for (int k = 0; k < 384; k++) {
    float2 bv = *(const float2*)Bp; Bp += INNER;
    fma2(a0, A0[k], bv); fma2(a1, A1[k], bv);
  }
  int m = m0 + rg * 2;
  float* dst = mmp + (size_t)ks * (256 * INNER);
  *(float2*)(dst + (size_t)m * INNER + col) = a0;
  *(float2*)(dst + (size_t)(m + 1) * INNER + col) = a1;
}

// ========== Stage 7: out partial (384) =====================================
__global__ __launch_bounds__(256) void k_s7(
    const float* __restrict__ mmp, const float* __restrict__ bv,
    const float* __restrict__ me, const float* __restrict__ We,
    float* __restrict__ op) {
  __shared__ float AL[1024];
  int bid = blockIdx.x, t = threadIdx.x;
  int ks = bid & 1, dc = (bid >> 1) % 3, mb = bid / 6;
  int m0 = mb * 4, k0 = ks * 256;
  const float* mp0 = mmp;
  const float* mp1 = mmp + 256 * INNER;
#pragma unroll
  for (int p = 0; p < 4; p++) {
    int idx = p * 256 + t, r = idx >> 8, k = idx & 255;
    int i = k0 + k;
    size_t off = (size_t)(m0 + r) * INNER + i;
    AL[idx] = (mp0[off] + mp1[off] + bv[i]) * me[off];
  }
  __syncthreads();
  int kl = t & 63, rg = t >> 6;
  int col = dc * 256 + 4 * kl;
  const float* Bp = We + (size_t)k0 * DD + col;
  const float* A0 = AL + rg * 256;
  float4 a = {0, 0, 0, 0};
#pragma unroll 4
  for (int k = 0; k < 256; k++) {
    float4 bvv = *(const float4*)Bp; Bp += DD;
    fma4(a, A0[k], bvv);
  }
  float* dst = op + (size_t)ks * (256 * DD);
  *(float4*)(dst + (size_t)(m0 + rg) * DD + col) = a;
}

// ========== Stage 8: epilogue (256) ========================================
__global__ __launch_bounds__(256) void k_s8(
    const float* __restrict__ op, const float* __restrict__ be,
    const float* __restrict__ gamma, const float* __restrict__ rs,
    float* __restrict__ outp) {
  int m = blockIdx.x, t = threadIdx.x;
  const float* o0 = op;
  const float* o1 = op + 256 * DD;
#pragma unroll
  for (int j = 0; j < 3; j++) {
    int d = t + j * 256;
    size_t off = (size_t)m * DD + d;
    outp[off] = rs[off] + (o0[off] + o1[off] + be[d]) * gamma[d];
  }
}

extern "C" void kernel_launch(void* const* d_in, const int* in_sizes, int n_in,
                              void* d_out, int out_size, void* d_ws, size_t ws_size,
                              hipStream_t stream) {
  const float* rs     = (const float*)d_in[0];
  const float* codes  = (const float*)d_in[1];
  const float* ss     = (const float*)d_in[2];
  const float* ln_r_g = (const float*)d_in[3];
  const float* ln_r_b = (const float*)d_in[4];
  const float* ln_s_g = (const float*)d_in[5];
  const float* ln_s_b = (const float*)d_in[6];
  const float* Wq  = (const float*)d_in[7];
  const float* bq  = (const float*)d_in[8];
  const float* Wmq = (const float*)d_in[9];
  const float* Wk  = (const float*)d_in[10];
  const float* bk  = (const float*)d_in[11];
  const float* Wmk = (const float*)d_in[12];
  const float* Wv  = (const float*)d_in[13];
  const float* bv  = (const float*)d_in[14];
  const float* Wmv = (const float*)d_in[15];
  const float* We  = (const float*)d_in[16];
  const float* be  = (const float*)d_in[17];
  const float* Wme = (const float*)d_in[18];
  const float* gamma = (const float*)d_in[19];

  float* w    = (float*)d_ws;
  float* s_ln = w;                       // 786432
  float* r_ln = s_ln + 786432;           // 196608
  float* sT   = r_ln + 196608;           // 786432
  float* WkT  = sT + 786432;             // 393216
  float* mq   = WkT + 393216;            // 196608
  float* mk   = mq + 196608;             // 196608
  float* mv   = mk + 196608;             // 196608
  float* me   = mv + 196608;             // 131072
  float* qp   = me + 131072;             // 2*131072
  float* qbk  = qp + 262144;             // 2048
  float* qm   = qbk + 2048;              // 1572864
  float* scp  = qm + 1572864;            // 2*524288
  float* mmp  = scp + 1048576;           // 2*131072
  float* op   = mmp + 262144;            // 2*196608
  float* wsm  = qm;                      // alias: qm dead after stage 4
  // total ≈ 25.7 MB

  k_s1<<<dim3(2080), 256, 0, stream>>>(ss, rs, ln_s_g, ln_s_b, ln_r_g, ln_r_b,
                                       codes, Wmq, Wmk, Wmv, Wme, Wk,
                                       s_ln, r_ln, mq, mk, mv, me, WkT);
  k_s2<<<dim3(448), 256, 0, stream>>>(s_ln, r_ln, mq, Wq, sT, qp);
  k_s3<<<dim3(1024), 256, 0, stream>>>(qp, bq, WkT, mk, bk, qm, qbk);
  k_s4<<<dim3(512), 256, 0, stream>>>(qm, sT, scp);
  k_s5<<<dim3(768), 256, 0, stream>>>(scp, qbk, s_ln, mv, wsm);
  k_s6<<<dim3(256), 256, 0, stream>>>(wsm, Wv, mmp);
  k_s7<<<dim3(384), 256, 0, stream>>>(mmp, bv, me, We, op);
  k_s8<<<dim3(256), 256, 0, stream>>>(op, be, gamma, rs, (float*)d_out);
}

// Round 6
// 258.927 us; speedup vs baseline: 1.6528x; 1.0994x over previous
//
#include <hip/hip_runtime.h>

// ReadInAttention — 8-stage f32 pipeline, fat-tile GEMM template:
// 16 rows x 256 cols per block, thread = 4 rows x float4 (16 acc),
// B streamed coalesced float4 w/ unroll-8 (8 loads in flight),
// A staged in LDS (broadcast reads). Deep k-splits for TLP.

#define DD 768
#define CDIM 384
#define NH 8
#define HD 64
#define INNER 512
#define VV 256

__device__ __forceinline__ void fma4(float4& a, float s, const float4& b) {
  a.x += s * b.x; a.y += s * b.y; a.z += s * b.z; a.w += s * b.w;
}

// ============ Stage 1: code GEMM [0,176) | WkT [176,272) | LN [272,1552) ====
__global__ __launch_bounds__(256) void k_s1(
    const float* __restrict__ ss, const float* __restrict__ rs,
    const float* __restrict__ g_s, const float* __restrict__ b_s,
    const float* __restrict__ g_r, const float* __restrict__ b_r,
    const float* __restrict__ codes, const float* __restrict__ Wmq,
    const float* __restrict__ Wmk, const float* __restrict__ Wmv,
    const float* __restrict__ Wme, const float* __restrict__ Wk,
    float* __restrict__ s_ln, float* __restrict__ r_ln,
    float* __restrict__ mq, float* __restrict__ mk, float* __restrict__ mv,
    float* __restrict__ me, float* __restrict__ WkT) {
  __shared__ float SB[6144];
  int bid = blockIdx.x, t = threadIdx.x;
  if (bid < 176) {             // ---- code GEMM: 16 rows x 256 cols, K=384 ---
    int nc = bid % 11, mb = bid / 11;
    int base = nc * 256;
    const float* W; float* outp; int N, colW;
    if (base < 768)       { W = Wmq; outp = mq; N = DD;    colW = base; }
    else if (base < 1536) { W = Wmk; outp = mk; N = DD;    colW = base - 768; }
    else if (base < 2304) { W = Wmv; outp = mv; N = DD;    colW = base - 1536; }
    else                  { W = Wme; outp = me; N = INNER; colW = base - 2304; }
    int m0 = mb * 16;
#pragma unroll
    for (int p = 0; p < 24; p++) {
      int idx = p * 256 + t, r = idx / 384, k = idx % 384;
      SB[idx] = codes[(size_t)(m0 + r) * CDIM + k];
    }
    __syncthreads();
    int kl = t & 63, wid = t >> 6;
    int col = colW + 4 * kl;
    const float* Bp = W + col;
    const float* A0 = SB + (wid * 4) * 384;
    float4 a0 = {0,0,0,0}, a1 = {0,0,0,0}, a2 = {0,0,0,0}, a3 = {0,0,0,0};
#pragma unroll 8
    for (int k = 0; k < 384; k++) {
      float4 bv = *(const float4*)Bp; Bp += N;
      fma4(a0, A0[k], bv); fma4(a1, A0[384 + k], bv);
      fma4(a2, A0[768 + k], bv); fma4(a3, A0[1152 + k], bv);
    }
    int m = m0 + wid * 4;
    float4 o0 = {1.f + a0.x, 1.f + a0.y, 1.f + a0.z, 1.f + a0.w};
    float4 o1 = {1.f + a1.x, 1.f + a1.y, 1.f + a1.z, 1.f + a1.w};
    float4 o2 = {1.f + a2.x, 1.f + a2.y, 1.f + a2.z, 1.f + a2.w};
    float4 o3 = {1.f + a3.x, 1.f + a3.y, 1.f + a3.z, 1.f + a3.w};
    *(float4*)(outp + (size_t)m * N + col) = o0;
    *(float4*)(outp + (size_t)(m + 1) * N + col) = o1;
    *(float4*)(outp + (size_t)(m + 2) * N + col) = o2;
    *(float4*)(outp + (size_t)(m + 3) * N + col) = o3;
  } else if (bid < 272) {      // ---- Wk transpose 768x512 -> 512x768 ----
    int tid = bid - 176;
    int d0 = (tid >> 3) * 64, c0 = (tid & 7) * 64;
    int j = t & 63, i0 = t >> 6;
#pragma unroll
    for (int p = 0; p < 16; p++) {
      int i = p * 4 + i0;
      SB[i * 65 + j] = Wk[(size_t)(d0 + i) * INNER + c0 + j];
    }
    __syncthreads();
#pragma unroll
    for (int p = 0; p < 16; p++) {
      int i = p * 4 + i0;
      WkT[(size_t)(c0 + i) * DD + d0 + j] = SB[j * 65 + i];
    }
  } else {                     // ---- LayerNorm, one row per block ----
    int rr = bid - 272;
    const float *x, *g, *bb; float* y; int r;
    if (rr < 1024) { x = ss; g = g_s; bb = b_s; y = s_ln; r = rr; }
    else           { x = rs; g = g_r; bb = b_r; y = r_ln; r = rr - 1024; }
    const float* xr = x + (size_t)r * DD;
    float v0 = xr[t], v1 = xr[t + 256], v2 = xr[t + 512];
    float s = v0 + v1 + v2, sq = v0*v0 + v1*v1 + v2*v2;
    for (int o = 32; o > 0; o >>= 1) {
      s += __shfl_down(s, o, 64); sq += __shfl_down(sq, o, 64);
    }
    int wid = t >> 6, lane = t & 63;
    if (lane == 0) { SB[wid] = s; SB[wid + 4] = sq; }
    __syncthreads();
    float sum = SB[0] + SB[1] + SB[2] + SB[3];
    float ssq = SB[4] + SB[5] + SB[6] + SB[7];
    float mu = sum * (1.0f / 768.0f);
    float var = ssq * (1.0f / 768.0f) - mu * mu;
    float rstd = rsqrtf(var + 1e-5f);
    float* yr = y + (size_t)r * DD;
    yr[t]       = (v0 - mu) * rstd * g[t]       + bb[t];
    yr[t + 256] = (v1 - mu) * rstd * g[t + 256] + bb[t + 256];
    yr[t + 512] = (v2 - mu) * rstd * g[t + 512] + bb[t + 512];
  }
}

// ============ Stage 2: q partial [0,128) | sT transpose [128,320) ===========
__global__ __launch_bounds__(256) void k_s2(
    const float* __restrict__ s_ln, const float* __restrict__ r_ln,
    const float* __restrict__ mq, const float* __restrict__ Wq,
    float* __restrict__ sT, float* __restrict__ qp) {
  __shared__ float SB[4160];
  int bid = blockIdx.x, t = threadIdx.x;
  if (bid < 128) {             // ---- q: 16 rows x 256 cols, Kc=192, ks=4 ----
    int mb = bid & 15, rem = bid >> 4, nc = rem & 1, ks = rem >> 1;
    int m0 = mb * 16, col0 = nc * 256, k0 = ks * 192;
#pragma unroll
    for (int p = 0; p < 12; p++) {
      int idx = p * 256 + t, r = idx / 192, k = idx % 192;
      size_t off = (size_t)(m0 + r) * DD + k0 + k;
      SB[idx] = r_ln[off] * mq[off];
    }
    __syncthreads();
    int kl = t & 63, wid = t >> 6;
    int col = col0 + 4 * kl;
    const float* Bp = Wq + (size_t)k0 * INNER + col;
    const float* A0 = SB + (wid * 4) * 192;
    float4 a0 = {0,0,0,0}, a1 = {0,0,0,0}, a2 = {0,0,0,0}, a3 = {0,0,0,0};
#pragma unroll 8
    for (int k = 0; k < 192; k++) {
      float4 bv = *(const float4*)Bp; Bp += INNER;
      fma4(a0, A0[k], bv); fma4(a1, A0[192 + k], bv);
      fma4(a2, A0[384 + k], bv); fma4(a3, A0[576 + k], bv);
    }
    int m = m0 + wid * 4;
    float* dst = qp + (size_t)ks * (256 * INNER);
    *(float4*)(dst + (size_t)m * INNER + col) = a0;
    *(float4*)(dst + (size_t)(m + 1) * INNER + col) = a1;
    *(float4*)(dst + (size_t)(m + 2) * INNER + col) = a2;
    *(float4*)(dst + (size_t)(m + 3) * INNER + col) = a3;
  } else {                     // ---- sT[b][d][v] ----
    int tid = bid - 128;
    int vt = tid & 3, dt = (tid >> 2) % 12, b = tid / 48;
    int v0 = vt * 64, d0 = dt * 64;
    int j = t & 63, i0 = t >> 6;
#pragma unroll
    for (int p = 0; p < 16; p++) {
      int i = p * 4 + i0;
      SB[i * 65 + j] = s_ln[(size_t)(b * VV + v0 + i) * DD + d0 + j];
    }
    __syncthreads();
#pragma unroll
    for (int p = 0; p < 16; p++) {
      int i = p * 4 + i0;
      sT[((size_t)b * DD + d0 + i) * VV + v0 + j] = SB[j * 65 + i];
    }
  }
}

// ============ Stage 3: qmk [0,384) | qbk [384,640) ==========================
__global__ __launch_bounds__(256) void k_s3(
    const float* __restrict__ qp, const float* __restrict__ bq,
    const float* __restrict__ WkT, const float* __restrict__ mk,
    const float* __restrict__ bk, float* __restrict__ qm,
    float* __restrict__ qbk) {
  __shared__ float SB[1024];
  int bid = blockIdx.x, t = threadIdx.x;
  if (bid < 384) {             // ---- qm: 16 rows x 256 d-cols, K=64 ----
    int h = bid & 7, dc = (bid >> 3) % 3, mb = bid / 24;
    int m0 = mb * 16;
#pragma unroll
    for (int p = 0; p < 4; p++) {
      int idx = p * 256 + t, r = idx >> 6, c = idx & 63;
      int i = h * HD + c;
      size_t off = (size_t)(m0 + r) * INNER + i;
      SB[idx] = qp[off] + qp[131072 + off] + qp[262144 + off] +
                qp[393216 + off] + bq[i];
    }
    __syncthreads();
    int kl = t & 63, wid = t >> 6;
    int col = dc * 256 + 4 * kl;
    const float* Bp = WkT + (size_t)(h * HD) * DD + col;
    const float* A0 = SB + (wid * 4) * HD;
    float4 a0 = {0,0,0,0}, a1 = {0,0,0,0}, a2 = {0,0,0,0}, a3 = {0,0,0,0};
#pragma unroll 8
    for (int k = 0; k < HD; k++) {
      float4 bv = *(const float4*)Bp; Bp += DD;
      fma4(a0, A0[k], bv); fma4(a1, A0[64 + k], bv);
      fma4(a2, A0[128 + k], bv); fma4(a3, A0[192 + k], bv);
    }
#pragma unroll
    for (int j = 0; j < 4; j++) {
      float4 a = (j == 0) ? a0 : (j == 1) ? a1 : (j == 2) ? a2 : a3;
      int m = m0 + wid * 4 + j;
      float4 mk4 = *(const float4*)(mk + (size_t)m * DD + col);
      float4 o = {a.x * mk4.x, a.y * mk4.y, a.z * mk4.z, a.w * mk4.w};
      *(float4*)(qm + ((size_t)m * NH + h) * DD + col) = o;
    }
  } else {                     // ---- qbk[m][h] ----
    int m = bid - 384;
    size_t off = (size_t)m * INNER;
    SB[t] = (qp[off + t] + qp[131072 + off + t] + qp[262144 + off + t] +
             qp[393216 + off + t] + bq[t]) * bk[t];
    int t2 = t + 256;
    SB[t2] = (qp[off + t2] + qp[131072 + off + t2] + qp[262144 + off + t2] +
              qp[393216 + off + t2] + bq[t2]) * bk[t2];
    __syncthreads();
    if (t < 8) {
      float a = 0.f;
      for (int c = 0; c < HD; c++) a += SB[t * HD + c];
      qbk[m * NH + t] = a;
    }
  }
}

// ============ Stage 4: scores partial (512 blocks, Kc=192, ks=4) ============
__global__ __launch_bounds__(256) void k_s4(
    const float* __restrict__ qm, const float* __restrict__ sT,
    float* __restrict__ scp) {
  __shared__ float SB[3072];
  int bid = blockIdx.x, t = threadIdx.x;
  int ks = bid & 3, b = (bid >> 2) & 3, mb = bid >> 4;
  int gi0 = b * 512 + mb * 16, k0 = ks * 192;
#pragma unroll
  for (int p = 0; p < 12; p++) {
    int idx = p * 256 + t, r = idx / 192, k = idx % 192;
    SB[idx] = qm[(size_t)(gi0 + r) * DD + k0 + k];
  }
  __syncthreads();
  int kl = t & 63, wid = t >> 6;
  int col = 4 * kl;
  const float* Bp = sT + ((size_t)b * DD + k0) * VV + col;
  const float* A0 = SB + (wid * 4) * 192;
  float4 a0 = {0,0,0,0}, a1 = {0,0,0,0}, a2 = {0,0,0,0}, a3 = {0,0,0,0};
#pragma unroll 8
  for (int k = 0; k < 192; k++) {
    float4 bv = *(const float4*)Bp; Bp += VV;
    fma4(a0, A0[k], bv); fma4(a1, A0[192 + k], bv);
    fma4(a2, A0[384 + k], bv); fma4(a3, A0[576 + k], bv);
  }
  int gi = gi0 + wid * 4;
  float* dst = scp + (size_t)ks * (2048 * VV);
  *(float4*)(dst + (size_t)gi * VV + col) = a0;
  *(float4*)(dst + (size_t)(gi + 1) * VV + col) = a1;
  *(float4*)(dst + (size_t)(gi + 2) * VV + col) = a2;
  *(float4*)(dst + (size_t)(gi + 3) * VV + col) = a3;
}

// ============ Stage 5: softmax + ws GEMM (384 blocks) =======================
__global__ __launch_bounds__(256) void k_s5(
    const float* __restrict__ scp, const float* __restrict__ qbk,
    const float* __restrict__ s_ln, const float* __restrict__ mvp,
    float* __restrict__ wsm) {
  __shared__ float SC[4096];
  int bid = blockIdx.x, t = threadIdx.x;
  int dc = bid % 3, up = (bid / 3) % 32, b = bid / 96;
  int gi0 = b * 512 + up * 16;
#pragma unroll
  for (int p = 0; p < 16; p++) {
    int idx = p * 256 + t, r = idx >> 8, c = idx & 255;
    size_t o = (size_t)(gi0 + r) * VV + c;
    float v = scp[o] + scp[524288 + o] + scp[1048576 + o] + scp[1572864 + o];
    int m = b * 64 + up * 2 + (r >> 3), h = r & 7;
    SC[idx] = (v + qbk[m * NH + h]) * 0.125f;
  }
  __syncthreads();
  int wid = t >> 6, lane = t & 63;
#pragma unroll
  for (int j = 0; j < 4; j++) {
    int r = wid * 4 + j;
    float x0 = SC[r * 256 + lane],       x1 = SC[r * 256 + lane + 64];
    float x2 = SC[r * 256 + lane + 128], x3 = SC[r * 256 + lane + 192];
    float mx = fmaxf(fmaxf(x0, x1), fmaxf(x2, x3));
    for (int o = 1; o < 64; o <<= 1) mx = fmaxf(mx, __shfl_xor(mx, o, 64));
    float e0 = __expf(x0 - mx), e1 = __expf(x1 - mx);
    float e2 = __expf(x2 - mx), e3 = __expf(x3 - mx);
    float sm = e0 + e1 + e2 + e3;
    for (int o = 1; o < 64; o <<= 1) sm += __shfl_xor(sm, o, 64);
    float rinv = 1.0f / sm;
    SC[r * 256 + lane] = e0 * rinv;       SC[r * 256 + lane + 64] = e1 * rinv;
    SC[r * 256 + lane + 128] = e2 * rinv; SC[r * 256 + lane + 192] = e3 * rinv;
  }
  __syncthreads();
  int kl = t & 63;
  int col = dc * 256 + 4 * kl;
  const float* Bp = s_ln + (size_t)(b * VV) * DD + col;
  const float* A0 = SC + (wid * 4) * 256;
  float4 a0 = {0,0,0,0}, a1 = {0,0,0,0}, a2 = {0,0,0,0}, a3 = {0,0,0,0};
#pragma unroll 8
  for (int v = 0; v < VV; v++) {
    float4 bv = *(const float4*)Bp; Bp += DD;
    fma4(a0, A0[v], bv); fma4(a1, A0[256 + v], bv);
    fma4(a2, A0[512 + v], bv); fma4(a3, A0[768 + v], bv);
  }
#pragma unroll
  for (int j = 0; j < 4; j++) {
    float4 a = (j == 0) ? a0 : (j == 1) ? a1 : (j == 2) ? a2 : a3;
    int r = wid * 4 + j;
    int ul = r >> 3, h = r & 7, m = b * 64 + up * 2 + ul;
    float4 mv4 = *(const float4*)(mvp + (size_t)m * DD + col);
    float4 o = {a.x * mv4.x, a.y * mv4.y, a.z * mv4.z, a.w * mv4.w};
    *(float4*)(wsm + ((size_t)h * 256 + m) * DD + col) = o;
  }
}

// ============ Stage 6: msg partial (256 blocks, 4 heads, Kc=96, ks=8) =======
__global__ __launch_bounds__(256) void k_s6(
    const float* __restrict__ wsm, const float* __restrict__ Wv,
    float* __restrict__ mmp) {
  __shared__ float AL[6144];
  int bid = blockIdx.x, t = threadIdx.x;
  int hp = bid & 1, ks = (bid >> 1) & 7, mb = bid >> 4;
  int h0 = hp * 4, m0 = mb * 16, k0 = ks * 96;
#pragma unroll
  for (int p = 0; p < 24; p++) {
    int idx = p * 256 + t;
    int e = idx / 1536, rem = idx % 1536, r = rem / 96, k = rem % 96;
    AL[idx] = wsm[((size_t)(h0 + e) * 256 + m0 + r) * DD + k0 + k];
  }
  __syncthreads();
  int kl = t & 63, wid = t >> 6;
  int hs = kl >> 4;              // head within group 0..3
  int c4 = 4 * (kl & 15);        // col within head
  int colg = h0 * HD + hs * HD + c4;
  const float* Bp = Wv + (size_t)k0 * INNER + colg;
  const float* A0 = AL + (hs * 16 + wid * 4) * 96;
  float4 a0 = {0,0,0,0}, a1 = {0,0,0,0}, a2 = {0,0,0,0}, a3 = {0,0,0,0};
#pragma unroll 8
  for (int k = 0; k < 96; k++) {
    float4 bv = *(const float4*)Bp; Bp += INNER;
    fma4(a0, A0[k], bv); fma4(a1, A0[96 + k], bv);
    fma4(a2, A0[192 + k], bv); fma4(a3, A0[288 + k], bv);
  }
  float* dst = mmp + (size_t)ks * (256 * INNER);
  int m = m0 + wid * 4;
  *(float4*)(dst + (size_t)m * INNER + colg) = a0;
  *(float4*)(dst + (size_t)(m + 1) * INNER + colg) = a1;
  *(float4*)(dst + (size_t)(m + 2) * INNER + colg) = a2;
  *(float4*)(dst + (size_t)(m + 3) * INNER + colg) = a3;
}

// ============ Stage 7: out partial (192 blocks, Kc=128, ks=4) ===============
__global__ __launch_bounds__(256) void k_s7(
    const float* __restrict__ mmp, const float* __restrict__ bvv,
    const float* __restrict__ me, const float* __restrict__ We,
    float* __restrict__ op) {
  __shared__ float AL[2048];
  int bid = blockIdx.x, t = threadIdx.x;
  int ks = bid & 3, dc = (bid >> 2) % 3, mb = bid / 12;
  int m0 = mb * 16, k0 = ks * 128;
#pragma unroll
  for (int p = 0; p < 8; p++) {
    int idx = p * 256 + t, r = idx >> 7, k = idx & 127;
    int i = k0 + k;
    size_t off = (size_t)(m0 + r) * INNER + i;
    float v = mmp[off] + mmp[131072 + off] + mmp[262144 + off] +
              mmp[393216 + off] + mmp[524288 + off] + mmp[655360 + off] +
              mmp[786432 + off] + mmp[917504 + off];
    AL[idx] = (v + bvv[i]) * me[off];
  }
  __syncthreads();
  int kl = t & 63, wid = t >> 6;
  int col = dc * 256 + 4 * kl;
  const float* Bp = We + (size_t)k0 * DD + col;
  const float* A0 = AL + (wid * 4) * 128;
  float4 a0 = {0,0,0,0}, a1 = {0,0,0,0}, a2 = {0,0,0,0}, a3 = {0,0,0,0};
#pragma unroll 8
  for (int k = 0; k < 128; k++) {
    float4 bv = *(const float4*)Bp; Bp += DD;
    fma4(a0, A0[k], bv); fma4(a1, A0[128 + k], bv);
    fma4(a2, A0[256 + k], bv); fma4(a3, A0[384 + k], bv);
  }
  float* dst = op + (size_t)ks * (256 * DD);
  int m = m0 + wid * 4;
  *(float4*)(dst + (size_t)m * DD + col) = a0;
  *(float4*)(dst + (size_t)(m + 1) * DD + col) = a1;
  *(float4*)(dst + (size_t)(m + 2) * DD + col) = a2;
  *(float4*)(dst + (size_t)(m + 3) * DD + col) = a3;
}

// ============ Stage 8: epilogue (256 blocks) ================================
__global__ __launch_bounds__(256) void k_s8(
    const float* __restrict__ op, const float* __restrict__ be,
    const float* __restrict__ gamma, const float* __restrict__ rs,
    float* __restrict__ outp) {
  int m = blockIdx.x, t = threadIdx.x;
#pragma unroll
  for (int j = 0; j < 3; j++) {
    int d = t + j * 256;
    size_t off = (size_t)m * DD + d;
    float v = op[off] + op[196608 + off] + op[393216 + off] + op[589824 + off];
    outp[off] = rs[off] + (v + be[d]) * gamma[d];
  }
}

extern "C" void kernel_launch(void* const* d_in, const int* in_sizes, int n_in,
                              void* d_out, int out_size, void* d_ws, size_t ws_size,
                              hipStream_t stream) {
  const float* rs     = (const float*)d_in[0];
  const float* codes  = (const float*)d_in[1];
  const float* ss     = (const float*)d_in[2];
  const float* ln_r_g = (const float*)d_in[3];
  const float* ln_r_b = (const float*)d_in[4];
  const float* ln_s_g = (const float*)d_in[5];
  const float* ln_s_b = (const float*)d_in[6];
  const float* Wq  = (const float*)d_in[7];
  const float* bq  = (const float*)d_in[8];
  const float* Wmq = (const float*)d_in[9];
  const float* Wk  = (const float*)d_in[10];
  const float* bk  = (const float*)d_in[11];
  const float* Wmk = (const float*)d_in[12];
  const float* Wv  = (const float*)d_in[13];
  const float* bv  = (const float*)d_in[14];
  const float* Wmv = (const float*)d_in[15];
  const float* We  = (const float*)d_in[16];
  const float* be  = (const float*)d_in[17];
  const float* Wme = (const float*)d_in[18];
  const float* gamma = (const float*)d_in[19];

  float* w = (float*)d_ws;
  // liveness-aliased layout (floats):
  float* s_ln = w;                 // @0        786432  (s1 -> s5)
  float* r_ln = w + 786432;        //           196608  (s1 -> s2)
  float* sT   = w + 983040;        //           786432  (s2 -> s4)
  float* WkT  = w + 1769472;       //           393216  (s1 -> s3)
  float* mq   = w + 2162688;       //           196608  (s1 -> s2)
  float* mk   = w + 2359296;       //           196608  (s1 -> s3)
  float* mv   = w + 2555904;       //           196608  (s1 -> s5)
  float* me   = w + 2752512;       //           131072  (s1 -> s7)
  float* qp   = w + 2883584;       //           524288  (s2 -> s3, 4 partials)
  float* qbk  = w + 3407872;       //             2048  (s3 -> s5)
  float* qm   = w + 3409920;       //          1572864  (s3 -> s4)
  float* scp  = w + 4982784;       //          2097152  (s4 -> s5, 4 partials)
  float* wsm  = qm;                // alias: qm dead after s4 (s5 -> s6)
  float* mmp  = sT;                // alias: sT+WkT dead after s4 (s6 -> s7, 8 partials)
  float* op   = scp;               // alias: scp dead after s5 (s7 -> s8, 4 partials)
  // peak = 4982784 + 2097152 floats ≈ 28.3 MB

  k_s1<<<dim3(1552), 256, 0, stream>>>(ss, rs, ln_s_g, ln_s_b, ln_r_g, ln_r_b,
                                       codes, Wmq, Wmk, Wmv, Wme, Wk,
                                       s_ln, r_ln, mq, mk, mv, me, WkT);
  k_s2<<<dim3(320), 256, 0, stream>>>(s_ln, r_ln, mq, Wq, sT, qp);
  k_s3<<<dim3(640), 256, 0, stream>>>(qp, bq, WkT, mk, bk, qm, qbk);
  k_s4<<<dim3(512), 256, 0, stream>>>(qm, sT, scp);
  k_s5<<<dim3(384), 256, 0, stream>>>(scp, qbk, s_ln, mv, wsm);
  k_s6<<<dim3(256), 256, 0, stream>>>(wsm, Wv, mmp);
  k_s7<<<dim3(192), 256, 0, stream>>>(mmp, bv, me, We, op);
  k_s8<<<dim3(256), 256, 0, stream>>>(op, be, gamma, rs, (float*)d_out);
}

// Round 7
// 198.151 us; speedup vs baseline: 2.1597x; 1.3067x over previous
//
#include <hip/hip_runtime.h>

// ReadInAttention — 8-stage f32 pipeline with software-pipelined GEMM core.
// gcore: 4 rows x float4 cols per thread, dual 8-deep float4 prefetch
// buffers (8-16 loads in flight), A broadcast from LDS.

#define DD 768
#define CDIM 384
#define NH 8
#define HD 64
#define INNER 512
#define VV 256

__device__ __forceinline__ void fma4(float4& a, float s, const float4& b) {
  a.x += s * b.x; a.y += s * b.y; a.z += s * b.z; a.w += s * b.w;
}

// K must be a multiple of 16.
template <int K, int NS>
__device__ __forceinline__ void gcore(const float* __restrict__ A0, int lda,
                                      const float* __restrict__ Bp,
                                      float4& a0, float4& a1, float4& a2,
                                      float4& a3) {
  float4 b0[8], b1[8];
#pragma unroll
  for (int i = 0; i < 8; i++) b0[i] = *(const float4*)(Bp + (size_t)i * NS);
  const float* Bq = Bp + (size_t)8 * NS;
#pragma unroll 1
  for (int kk = 0; kk < K; kk += 16) {
#pragma unroll
    for (int i = 0; i < 8; i++) b1[i] = *(const float4*)(Bq + (size_t)i * NS);
    Bq += (size_t)8 * NS;
#pragma unroll
    for (int i = 0; i < 8; i++) {
      float4 bv = b0[i]; int k = kk + i;
      fma4(a0, A0[k], bv); fma4(a1, A0[lda + k], bv);
      fma4(a2, A0[2 * lda + k], bv); fma4(a3, A0[3 * lda + k], bv);
    }
    if (kk + 16 < K) {
#pragma unroll
      for (int i = 0; i < 8; i++) b0[i] = *(const float4*)(Bq + (size_t)i * NS);
      Bq += (size_t)8 * NS;
    }
#pragma unroll
    for (int i = 0; i < 8; i++) {
      float4 bv = b1[i]; int k = kk + 8 + i;
      fma4(a0, A0[k], bv); fma4(a1, A0[lda + k], bv);
      fma4(a2, A0[2 * lda + k], bv); fma4(a3, A0[3 * lda + k], bv);
    }
  }
}

// ===== Stage 1: code GEMM [0,176) | WkT [176,272) | LN [272,1552) ==========
__global__ __launch_bounds__(256, 2) void k_s1(
    const float* __restrict__ ss, const float* __restrict__ rs,
    const float* __restrict__ g_s, const float* __restrict__ b_s,
    const float* __restrict__ g_r, const float* __restrict__ b_r,
    const float* __restrict__ codes, const float* __restrict__ Wmq,
    const float* __restrict__ Wmk, const float* __restrict__ Wmv,
    const float* __restrict__ Wme, const float* __restrict__ Wk,
    float* __restrict__ s_ln, float* __restrict__ r_ln,
    float* __restrict__ cp, float* __restrict__ WkT) {
  __shared__ float SB[6144];
  int bid = blockIdx.x, t = threadIdx.x;
  if (bid < 176) {  // ---- code GEMM: 16 rows x 256 cols, K=384 full ----
    int nc = bid % 11, mb = bid / 11;
    int base = nc * 256;
    const float* W; int N, colW;
    if (base < 768)       { W = Wmq; N = DD;    colW = base; }
    else if (base < 1536) { W = Wmk; N = DD;    colW = base - 768; }
    else if (base < 2304) { W = Wmv; N = DD;    colW = base - 1536; }
    else                  { W = Wme; N = INNER; colW = base - 2304; }
    int m0 = mb * 16;
#pragma unroll
    for (int p = 0; p < 24; p++) {
      int idx = p * 256 + t, r = idx / 384, k = idx % 384;
      SB[idx] = codes[(size_t)(m0 + r) * CDIM + k];
    }
    __syncthreads();
    int kl = t & 63, wid = t >> 6;
    const float* A0 = SB + (wid * 4) * 384;
    float4 a0 = {0,0,0,0}, a1 = {0,0,0,0}, a2 = {0,0,0,0}, a3 = {0,0,0,0};
    if (N == DD)
      gcore<384, DD>(A0, 384, W + colW + 4 * kl, a0, a1, a2, a3);
    else
      gcore<384, INNER>(A0, 384, W + colW + 4 * kl, a0, a1, a2, a3);
    int m = m0 + wid * 4, gcol = base + 4 * kl;
    *(float4*)(cp + (size_t)m * 2816 + gcol) = a0;
    *(float4*)(cp + (size_t)(m + 1) * 2816 + gcol) = a1;
    *(float4*)(cp + (size_t)(m + 2) * 2816 + gcol) = a2;
    *(float4*)(cp + (size_t)(m + 3) * 2816 + gcol) = a3;
  } else if (bid < 272) {  // ---- Wk transpose ----
    int tid = bid - 176;
    int d0 = (tid >> 3) * 64, c0 = (tid & 7) * 64;
    int j = t & 63, i0 = t >> 6;
#pragma unroll
    for (int p = 0; p < 16; p++) {
      int i = p * 4 + i0;
      SB[i * 65 + j] = Wk[(size_t)(d0 + i) * INNER + c0 + j];
    }
    __syncthreads();
#pragma unroll
    for (int p = 0; p < 16; p++) {
      int i = p * 4 + i0;
      WkT[(size_t)(c0 + i) * DD + d0 + j] = SB[j * 65 + i];
    }
  } else {  // ---- LayerNorm ----
    int rr = bid - 272;
    const float *x, *g, *bb; float* y; int r;
    if (rr < 1024) { x = ss; g = g_s; bb = b_s; y = s_ln; r = rr; }
    else           { x = rs; g = g_r; bb = b_r; y = r_ln; r = rr - 1024; }
    const float* xr = x + (size_t)r * DD;
    float v0 = xr[t], v1 = xr[t + 256], v2 = xr[t + 512];
    float s = v0 + v1 + v2, sq = v0 * v0 + v1 * v1 + v2 * v2;
    for (int o = 32; o > 0; o >>= 1) {
      s += __shfl_down(s, o, 64); sq += __shfl_down(sq, o, 64);
    }
    int wid = t >> 6, lane = t & 63;
    if (lane == 0) { SB[wid] = s; SB[wid + 4] = sq; }
    __syncthreads();
    float sum = SB[0] + SB[1] + SB[2] + SB[3];
    float ssq = SB[4] + SB[5] + SB[6] + SB[7];
    float mu = sum * (1.0f / 768.0f);
    float var = ssq * (1.0f / 768.0f) - mu * mu;
    float rstd = rsqrtf(var + 1e-5f);
    float* yr = y + (size_t)r * DD;
    yr[t]       = (v0 - mu) * rstd * g[t]       + bb[t];
    yr[t + 256] = (v1 - mu) * rstd * g[t + 256] + bb[t + 256];
    yr[t + 512] = (v2 - mu) * rstd * g[t + 512] + bb[t + 512];
  }
}

// ===== Stage 2: q partial [0,128) (Kc=192, ks=4) | sT [128,320) ============
__global__ __launch_bounds__(256, 2) void k_s2(
    const float* __restrict__ s_ln, const float* __restrict__ r_ln,
    const float* __restrict__ cp, const float* __restrict__ Wq,
    float* __restrict__ sT, float* __restrict__ qp) {
  __shared__ float SB[4160];
  int bid = blockIdx.x, t = threadIdx.x;
  if (bid < 128) {
    int ks = bid & 3, tile = bid >> 2, nc = tile & 1, mb = tile >> 1;
    int m0 = mb * 16, col0 = nc * 256, k0 = ks * 192;
#pragma unroll
    for (int p = 0; p < 12; p++) {
      int idx = p * 256 + t, r = idx / 192, k = idx % 192;
      int d = k0 + k;
      float mqv = cp[(size_t)(m0 + r) * 2816 + d] + 1.0f;
      SB[idx] = r_ln[(size_t)(m0 + r) * DD + d] * mqv;
    }
    __syncthreads();
    int kl = t & 63, wid = t >> 6;
    int col = col0 + 4 * kl;
    const float* A0 = SB + (wid * 4) * 192;
    float4 a0 = {0,0,0,0}, a1 = {0,0,0,0}, a2 = {0,0,0,0}, a3 = {0,0,0,0};
    gcore<192, INNER>(A0, 192, Wq + (size_t)k0 * INNER + col, a0, a1, a2, a3);
    int m = m0 + wid * 4;
    float* dst = qp + (size_t)ks * (256 * INNER);
    *(float4*)(dst + (size_t)m * INNER + col) = a0;
    *(float4*)(dst + (size_t)(m + 1) * INNER + col) = a1;
    *(float4*)(dst + (size_t)(m + 2) * INNER + col) = a2;
    *(float4*)(dst + (size_t)(m + 3) * INNER + col) = a3;
  } else {  // ---- sT[b][d][v] ----
    int tid = bid - 128;
    int vt = tid & 3, dt = (tid >> 2) % 12, b = tid / 48;
    int v0 = vt * 64, d0 = dt * 64;
    int j = t & 63, i0 = t >> 6;
#pragma unroll
    for (int p = 0; p < 16; p++) {
      int i = p * 4 + i0;
      SB[i * 65 + j] = s_ln[(size_t)(b * VV + v0 + i) * DD + d0 + j];
    }
    __syncthreads();
#pragma unroll
    for (int p = 0; p < 16; p++) {
      int i = p * 4 + i0;
      sT[((size_t)b * DD + d0 + i) * VV + v0 + j] = SB[j * 65 + i];
    }
  }
}

// ===== Stage 3: qmk [0,384) (K=64) | qbk [384,640) =========================
__global__ __launch_bounds__(256, 2) void k_s3(
    const float* __restrict__ qp, const float* __restrict__ bq,
    const float* __restrict__ WkT, const float* __restrict__ cp,
    const float* __restrict__ bk, float* __restrict__ qm,
    float* __restrict__ qbk) {
  __shared__ float SB[1024];
  int bid = blockIdx.x, t = threadIdx.x;
  if (bid < 384) {
    int h = bid & 7, dc = (bid >> 3) % 3, mb = bid / 24;
    int m0 = mb * 16;
#pragma unroll
    for (int p = 0; p < 4; p++) {
      int idx = p * 256 + t, r = idx >> 6, c = idx & 63;
      int i = h * HD + c;
      size_t off = (size_t)(m0 + r) * INNER + i;
      SB[idx] = qp[off] + qp[131072 + off] + qp[262144 + off] +
                qp[393216 + off] + bq[i];
    }
    __syncthreads();
    int kl = t & 63, wid = t >> 6;
    int col = dc * 256 + 4 * kl;
    const float* A0 = SB + (wid * 4) * HD;
    float4 a0 = {0,0,0,0}, a1 = {0,0,0,0}, a2 = {0,0,0,0}, a3 = {0,0,0,0};
    gcore<64, DD>(A0, HD, WkT + (size_t)(h * HD) * DD + col, a0, a1, a2, a3);
#pragma unroll
    for (int j = 0; j < 4; j++) {
      float4 a = (j == 0) ? a0 : (j == 1) ? a1 : (j == 2) ? a2 : a3;
      int m = m0 + wid * 4 + j;
      const float* mkp = cp + (size_t)m * 2816 + 768 + col;
      float4 o = {a.x * (mkp[0] + 1.0f), a.y * (mkp[1] + 1.0f),
                  a.z * (mkp[2] + 1.0f), a.w * (mkp[3] + 1.0f)};
      *(float4*)(qm + ((size_t)m * NH + h) * DD + col) = o;
    }
  } else {  // ---- qbk ----
    int m = bid - 384;
    size_t off = (size_t)m * INNER;
    SB[t] = (qp[off + t] + qp[131072 + off + t] + qp[262144 + off + t] +
             qp[393216 + off + t] + bq[t]) * bk[t];
    int t2 = t + 256;
    SB[t2] = (qp[off + t2] + qp[131072 + off + t2] + qp[262144 + off + t2] +
              qp[393216 + off + t2] + bq[t2]) * bk[t2];
    __syncthreads();
    if (t < 8) {
      float a = 0.f;
      for (int c = 0; c < HD; c++) a += SB[t * HD + c];
      qbk[m * NH + t] = a;
    }
  }
}

// ===== Stage 4: scores partial (512 blocks, Kc=192, ks=4) ==================
__global__ __launch_bounds__(256, 2) void k_s4(
    const float* __restrict__ qm, const float* __restrict__ sT,
    float* __restrict__ scp) {
  __shared__ float SB[3072];
  int bid = blockIdx.x, t = threadIdx.x;
  int ks = bid & 3, b = (bid >> 2) & 3, mb = bid >> 4;
  int gi0 = b * 512 + mb * 16, k0 = ks * 192;
#pragma unroll
  for (int p = 0; p < 12; p++) {
    int idx = p * 256 + t, r = idx / 192, k = idx % 192;
    SB[idx] = qm[(size_t)(gi0 + r) * DD + k0 + k];
  }
  __syncthreads();
  int kl = t & 63, wid = t >> 6;
  int col = 4 * kl;
  const float* A0 = SB + (wid * 4) * 192;
  float4 a0 = {0,0,0,0}, a1 = {0,0,0,0}, a2 = {0,0,0,0}, a3 = {0,0,0,0};
  gcore<192, VV>(A0, 192, sT + ((size_t)b * DD + k0) * VV + col, a0, a1, a2, a3);
  int gi = gi0 + wid * 4;
  float* dst = scp + (size_t)ks * (2048 * VV);
  *(float4*)(dst + (size_t)gi * VV + col) = a0;
  *(float4*)(dst + (size_t)(gi + 1) * VV + col) = a1;
  *(float4*)(dst + (size_t)(gi + 2) * VV + col) = a2;
  *(float4*)(dst + (size_t)(gi + 3) * VV + col) = a3;
}

// ===== Stage 5: softmax + ws GEMM (384 blocks, K=256) ======================
__global__ __launch_bounds__(256, 2) void k_s5(
    const float* __restrict__ scp, const float* __restrict__ qbk,
    const float* __restrict__ s_ln, const float* __restrict__ cp,
    float* __restrict__ wsm) {
  __shared__ float SC[4096];
  int bid = blockIdx.x, t = threadIdx.x;
  int dc = bid % 3, up = (bid / 3) % 32, b = bid / 96;
  int gi0 = b * 512 + up * 16;
#pragma unroll
  for (int p = 0; p < 16; p++) {
    int idx = p * 256 + t, r = idx >> 8, c = idx & 255;
    size_t o = (size_t)(gi0 + r) * VV + c;
    float v = scp[o] + scp[524288 + o] + scp[1048576 + o] + scp[1572864 + o];
    int m = b * 64 + up * 2 + (r >> 3), h = r & 7;
    SC[idx] = (v + qbk[m * NH + h]) * 0.125f;
  }
  __syncthreads();
  int wid = t >> 6, lane = t & 63;
#pragma unroll
  for (int j = 0; j < 4; j++) {
    int r = wid * 4 + j;
    float x0 = SC[r * 256 + lane],       x1 = SC[r * 256 + lane + 64];
    float x2 = SC[r * 256 + lane + 128], x3 = SC[r * 256 + lane + 192];
    float mx = fmaxf(fmaxf(x0, x1), fmaxf(x2, x3));
    for (int o = 1; o < 64; o <<= 1) mx = fmaxf(mx, __shfl_xor(mx, o, 64));
    float e0 = __expf(x0 - mx), e1 = __expf(x1 - mx);
    float e2 = __expf(x2 - mx), e3 = __expf(x3 - mx);
    float sm = e0 + e1 + e2 + e3;
    for (int o = 1; o < 64; o <<= 1) sm += __shfl_xor(sm, o, 64);
    float rinv = 1.0f / sm;
    SC[r * 256 + lane] = e0 * rinv;       SC[r * 256 + lane + 64] = e1 * rinv;
    SC[r * 256 + lane + 128] = e2 * rinv; SC[r * 256 + lane + 192] = e3 * rinv;
  }
  __syncthreads();
  int kl = t & 63;
  int col = dc * 256 + 4 * kl;
  const float* A0 = SC + (wid * 4) * 256;
  float4 a0 = {0,0,0,0}, a1 = {0,0,0,0}, a2 = {0,0,0,0}, a3 = {0,0,0,0};
  gcore<VV, DD>(A0, 256, s_ln + (size_t)(b * VV) * DD + col, a0, a1, a2, a3);
#pragma unroll
  for (int j = 0; j < 4; j++) {
    float4 a = (j == 0) ? a0 : (j == 1) ? a1 : (j == 2) ? a2 : a3;
    int r = wid * 4 + j;
    int ul = r >> 3, h = r & 7, m = b * 64 + up * 2 + ul;
    const float* mvp = cp + (size_t)m * 2816 + 1536 + col;
    float4 o = {a.x * (mvp[0] + 1.0f), a.y * (mvp[1] + 1.0f),
                a.z * (mvp[2] + 1.0f), a.w * (mvp[3] + 1.0f)};
    *(float4*)(wsm + ((size_t)h * 256 + m) * DD + col) = o;
  }
}

// ===== Stage 6: msg partial (256 blocks, Kc=96, ks=8) ======================
__global__ __launch_bounds__(256, 2) void k_s6(
    const float* __restrict__ wsm, const float* __restrict__ Wv,
    float* __restrict__ mmp) {
  __shared__ float AL[6144];
  int bid = blockIdx.x, t = threadIdx.x;
  int hp = bid & 1, ks = (bid >> 1) & 7, mb = bid >> 4;
  int h0 = hp * 4, m0 = mb * 16, k0 = ks * 96;
#pragma unroll
  for (int p = 0; p < 24; p++) {
    int idx = p * 256 + t;
    int e = idx / 1536, rem = idx % 1536, r = rem / 96, k = rem % 96;
    AL[idx] = wsm[((size_t)(h0 + e) * 256 + m0 + r) * DD + k0 + k];
  }
  __syncthreads();
  int kl = t & 63, wid = t >> 6;
  int hs = kl >> 4, c4 = 4 * (kl & 15);
  int colg = h0 * HD + hs * HD + c4;
  const float* A0 = AL + (hs * 16 + wid * 4) * 96;
  float4 a0 = {0,0,0,0}, a1 = {0,0,0,0}, a2 = {0,0,0,0}, a3 = {0,0,0,0};
  gcore<96, INNER>(A0, 96, Wv + (size_t)k0 * INNER + colg, a0, a1, a2, a3);
  float* dst = mmp + (size_t)ks * (256 * INNER);
  int m = m0 + wid * 4;
  *(float4*)(dst + (size_t)m * INNER + colg) = a0;
  *(float4*)(dst + (size_t)(m + 1) * INNER + colg) = a1;
  *(float4*)(dst + (size_t)(m + 2) * INNER + colg) = a2;
  *(float4*)(dst + (size_t)(m + 3) * INNER + colg) = a3;
}

// ===== Stage 7: out partial (384 blocks, Kc=64, ks=8) ======================
__global__ __launch_bounds__(256, 2) void k_s7(
    const float* __restrict__ mmp, const float* __restrict__ bvv,
    const float* __restrict__ cp, const float* __restrict__ We,
    float* __restrict__ op) {
  __shared__ float AL[1024];
  int bid = blockIdx.x, t = threadIdx.x;
  int ks = bid & 7, dc = (bid >> 3) % 3, mb = bid / 24;
  int m0 = mb * 16, k0 = ks * 64;
#pragma unroll
  for (int p = 0; p < 4; p++) {
    int idx = p * 256 + t, r = idx >> 6, k = idx & 63;
    int i = k0 + k;
    size_t off = (size_t)(m0 + r) * INNER + i;
    float v = mmp[off] + mmp[131072 + off] + mmp[262144 + off] +
              mmp[393216 + off] + mmp[524288 + off] + mmp[655360 + off] +
              mmp[786432 + off] + mmp[917504 + off];
    float mev = cp[(size_t)(m0 + r) * 2816 + 2304 + i] + 1.0f;
    AL[idx] = (v + bvv[i]) * mev;
  }
  __syncthreads();
  int kl = t & 63, wid = t >> 6;
  int col = dc * 256 + 4 * kl;
  const float* A0 = AL + (wid * 4) * 64;
  float4 a0 = {0,0,0,0}, a1 = {0,0,0,0}, a2 = {0,0,0,0}, a3 = {0,0,0,0};
  gcore<64, DD>(A0, 64, We + (size_t)k0 * DD + col, a0, a1, a2, a3);
  float* dst = op + (size_t)ks * (256 * DD);
  int m = m0 + wid * 4;
  *(float4*)(dst + (size_t)m * DD + col) = a0;
  *(float4*)(dst + (size_t)(m + 1) * DD + col) = a1;
  *(float4*)(dst + (size_t)(m + 2) * DD + col) = a2;
  *(float4*)(dst + (size_t)(m + 3) * DD + col) = a3;
}

// ===== Stage 8: epilogue (256 blocks) ======================================
__global__ __launch_bounds__(256) void k_s8(
    const float* __restrict__ op, const float* __restrict__ be,
    const float* __restrict__ gamma, const float* __restrict__ rs,
    float* __restrict__ outp) {
  int m = blockIdx.x, t = threadIdx.x;
#pragma unroll
  for (int j = 0; j < 3; j++) {
    int d = t + j * 256;
    size_t off = (size_t)m * DD + d;
    float v = op[off] + op[196608 + off] + op[393216 + off] +
              op[589824 + off] + op[786432 + off] + op[983040 + off] +
              op[1179648 + off] + op[1376256 + off];
    outp[off] = rs[off] + (v + be[d]) * gamma[d];
  }
}

extern "C" void kernel_launch(void* const* d_in, const int* in_sizes, int n_in,
                              void* d_out, int out_size, void* d_ws, size_t ws_size,
                              hipStream_t stream) {
  const float* rs     = (const float*)d_in[0];
  const float* codes  = (const float*)d_in[1];
  const float* ss     = (const float*)d_in[2];
  const float* ln_r_g = (const float*)d_in[3];
  const float* ln_r_b = (const float*)d_in[4];
  const float* ln_s_g = (const float*)d_in[5];
  const float* ln_s_b = (const float*)d_in[6];
  const float* Wq  = (const float*)d_in[7];
  const float* bq  = (const float*)d_in[8];
  const float* Wk  = (const float*)d_in[10];
  const float* bk  = (const float*)d_in[11];
  const float* Wmq = (const float*)d_in[9];
  const float* Wmk = (const float*)d_in[12];
  const float* Wv  = (const float*)d_in[13];
  const float* bv  = (const float*)d_in[14];
  const float* Wmv = (const float*)d_in[15];
  const float* We  = (const float*)d_in[16];
  const float* be  = (const float*)d_in[17];
  const float* Wme = (const float*)d_in[18];
  const float* gamma = (const float*)d_in[19];

  float* w = (float*)d_ws;
  // liveness-aliased layout (float offsets); peak ≈ 28.3 MB
  float* s_ln = w;                  // @0        786432  (s1 -> s5)
  float* r_ln = w + 786432;         //           196608  (s1 -> s2)
  float* WkT  = w + 983040;         //           393216  (s1 -> s3)
  float* qp   = w + 1376256;        //           524288  (s2 -> s3, 4 partials)
  float* sT   = w + 1900544;        //           786432  (s2 -> s4)
  float* cp   = w + 2686976;        //           720896  (s1 -> s7) [m][2816]
  float* qbk  = w + 3407872;        //             2048  (s3 -> s5)
  float* qm   = w + 3409920;        //          1572864  (s3 -> s4)
  float* scp  = w + 4982784;        //          2097152  (s4 -> s5, 4 partials)
  float* wsm  = qm;                 // alias (s5 -> s6)
  float* mmp  = r_ln;               // alias r_ln+WkT+qp region (s6 -> s7, 8 partials)
  float* op   = scp;                // alias (s7 -> s8, 8 partials)

  k_s1<<<dim3(1552), 256, 0, stream>>>(ss, rs, ln_s_g, ln_s_b, ln_r_g, ln_r_b,
                                       codes, Wmq, Wmk, Wmv, Wme, Wk,
                                       s_ln, r_ln, cp, WkT);
  k_s2<<<dim3(320), 256, 0, stream>>>(s_ln, r_ln, cp, Wq, sT, qp);
  k_s3<<<dim3(640), 256, 0, stream>>>(qp, bq, WkT, cp, bk, qm, qbk);
  k_s4<<<dim3(512), 256, 0, stream>>>(qm, sT, scp);
  k_s5<<<dim3(384), 256, 0, stream>>>(scp, qbk, s_ln, cp, wsm);
  k_s6<<<dim3(256), 256, 0, stream>>>(wsm, Wv, mmp);
  k_s7<<<dim3(384), 256, 0, stream>>>(mmp, bv, cp, We, op);
  k_s8<<<dim3(256), 256, 0, stream>>>(op, be, gamma, rs, (float*)d_out);
}